// Round 1
// 5599.559 us; speedup vs baseline: 1.0261x; 1.0261x over previous
//
#include <hip/hip_runtime.h>
#include <hip/hip_bf16.h>
#include <hip/hip_fp16.h>
#include <cmath>

using bf16 = __hip_bfloat16;
typedef __attribute__((ext_vector_type(8))) short short8;
typedef __attribute__((ext_vector_type(4))) float floatx4;

__device__ __forceinline__ void lds_load16(void* lds, const void* g) {
  __builtin_amdgcn_global_load_lds(
      (const __attribute__((address_space(1))) void*)g,
      (__attribute__((address_space(3))) void*)lds, 16, 0, 0);
}

// ---------------- generic BT GEMM: C[M][N] = scale*(A[M][K] x B[N][K]^T) + bias ----------
struct GemmP {
  const bf16* A; const bf16* B;
  int M, N, K, lda, ldb;
  long sAimg, sAh, sBimg, sBh;
  int ZH, cross;
  float scale;
  const float* bias;
  float* Cf; int ldcf; long sCfImg, sCfH;
  bf16* Cb; int ldcb; long sCbImg, sCbH;
  __half* Ch; int ldch; long sChImg, sChH;
  const float* resid;  // fp32, same indexing as Cf
};

template <int NTILE>  // 128: 4 waves x (64x64); 64: 4 waves x (32x64)
__global__ __launch_bounds__(256, 2)
void gemm_bt(GemmP p) {
  __shared__ __align__(16) bf16 As[128 * 32];
  __shared__ __align__(16) bf16 Bs[NTILE * 32];
  constexpr int MI = (NTILE == 128) ? 4 : 2;
  const int z = blockIdx.z;
  const int imgA = z / p.ZH;
  const int h = z - imgA * p.ZH;
  const int imgB = imgA ^ p.cross;
  const bf16* Ab = p.A + (long)imgA * p.sAimg + (long)h * p.sAh;
  const bf16* Bb = p.B + (long)imgB * p.sBimg + (long)h * p.sBh;
  const int m0 = blockIdx.y * 128, n0 = blockIdx.x * NTILE;
  const int t = threadIdx.x, w = t >> 6, l = t & 63;
  const int lr = l >> 2, lk = (l & 3) * 8;   // staging: row-in-chunk, k-elem offset
  const int fr = l & 15, fk = (l >> 4) * 8;  // fragment: row-in-16tile, k offset

  const bf16* aG0 = Ab + (long)(m0 + w * 16 + lr) * p.lda + lk;
  const bf16* aG1 = aG0 + (long)64 * p.lda;
  const bf16* bG0 = Bb + (long)(n0 + w * 16 + lr) * p.ldb + lk;
  const bf16* bG1 = bG0 + (long)64 * p.ldb;
  bf16* aL0 = &As[w * 16 * 32];
  bf16* aL1 = &As[(w + 4) * 16 * 32];
  bf16* bL0 = &Bs[w * 16 * 32];
  bf16* bL1 = &Bs[(w + 4) * 16 * 32];
  const int wr = (NTILE == 128) ? (w >> 1) * 64 : w * 32;
  const int wc = (NTILE == 128) ? (w & 1) * 64 : 0;

  floatx4 zero4 = {0.f, 0.f, 0.f, 0.f};
  floatx4 acc[MI][4];
#pragma unroll
  for (int i = 0; i < MI; i++)
#pragma unroll
    for (int j = 0; j < 4; j++) acc[i][j] = zero4;

  for (int k0 = 0; k0 < p.K; k0 += 32) {
    lds_load16(aL0, aG0 + k0);
    lds_load16(aL1, aG1 + k0);
    lds_load16(bL0, bG0 + k0);
    if (NTILE == 128) lds_load16(bL1, bG1 + k0);
    __syncthreads();
    short8 af[MI], bfv[4];
#pragma unroll
    for (int i = 0; i < MI; i++)
      af[i] = *(const short8*)&As[(wr + i * 16 + fr) * 32 + fk];
#pragma unroll
    for (int j = 0; j < 4; j++)
      bfv[j] = *(const short8*)&Bs[(wc + j * 16 + fr) * 32 + fk];
#pragma unroll
    for (int i = 0; i < MI; i++)
#pragma unroll
      for (int j = 0; j < 4; j++)
        acc[i][j] = __builtin_amdgcn_mfma_f32_16x16x32_bf16(af[i], bfv[j], acc[i][j], 0, 0, 0);
    __syncthreads();
  }

  // epilogue: D[row][col], col = lane&15, row = (lane>>4)*4 + r  [m89-verified layout]
  const int cl = l & 15, rq = (l >> 4) * 4;
  const long cfBase = (long)imgA * p.sCfImg + (long)h * p.sCfH;
  const long cbBase = (long)imgA * p.sCbImg + (long)h * p.sCbH;
  const long chBase = (long)imgA * p.sChImg + (long)h * p.sChH;
#pragma unroll
  for (int j = 0; j < 4; j++) {
    const int col = n0 + wc + j * 16 + cl;
    if (col >= p.N) continue;
    const float bv = p.bias ? p.bias[col] : 0.f;
#pragma unroll
    for (int i = 0; i < MI; i++) {
#pragma unroll
      for (int r = 0; r < 4; r++) {
        const int row = m0 + wr + i * 16 + rq + r;
        float val = acc[i][j][r] * p.scale + bv;
        if (p.resid) val += p.resid[cfBase + (long)row * p.ldcf + col];
        if (p.Cf) p.Cf[cfBase + (long)row * p.ldcf + col] = val;
        if (p.Cb) p.Cb[cbBase + (long)row * p.ldcb + col] = __float2bfloat16(val);
        if (p.Ch) p.Ch[chBase + (long)row * p.ldch + col] = __float2half(val);
      }
    }
  }
}

// ---------------- elementwise / helper kernels ----------------
__global__ __launch_bounds__(256)
void cvt_f2b(const float* __restrict__ in, bf16* __restrict__ out, long n) {
  long i = (long)blockIdx.x * 256 + threadIdx.x;
  const long stride = (long)gridDim.x * 256;
  for (; i < n; i += stride) out[i] = __float2bfloat16(in[i]);
}

// fused per-layer weight conversion into rotating buffer (5 MB):
// [0:768K) wqkv stacked | [768K:1M) wm(col-permuted) | [1M:2M) w1 | [2M:2.5M) w2
// plus packed qkv bias (1536 floats)
__global__ __launch_bounds__(256)
void cvt_layer(const float* __restrict__ Wq, const float* __restrict__ Wk,
               const float* __restrict__ Wv, const float* __restrict__ Wm,
               const float* __restrict__ W1, const float* __restrict__ W2,
               const float* __restrict__ bq, const float* __restrict__ bk,
               const float* __restrict__ bv,
               int layer, bf16* __restrict__ out, float* __restrict__ bqkv) {
  const long i = (long)blockIdx.x * 256 + threadIdx.x;
  if (i >= 2621440L + 1536) return;
  if (i >= 2621440L) {
    const int j = (int)(i - 2621440L);
    float b;
    if (j < 512) b = bq[layer * 512 + j];
    else if (j < 1024) b = bk[layer * 512 + j - 512];
    else b = bv[layer * 512 + j - 1024];
    bqkv[j] = b;
    return;
  }
  float v;
  if (i < 262144) {
    v = Wq[(long)layer * 262144 + i];
  } else if (i < 524288) {
    v = Wk[(long)layer * 262144 + i - 262144];
  } else if (i < 786432) {
    v = Wv[(long)layer * 262144 + i - 524288];
  } else if (i < 1048576) {
    const long j = i - 786432;
    const int o = (int)(j >> 9), cp = (int)(j & 511);
    v = Wm[(long)layer * 262144 + o * 512 + (cp & 63) * 8 + (cp >> 6)];
  } else if (i < 2097152) {
    v = W1[(long)layer * 1048576 + i - 1048576];
  } else {
    v = W2[(long)layer * 524288 + i - 2097152];
  }
  out[i] = __float2bfloat16(v);
}

__global__ __launch_bounds__(256)
void init_x(const float* __restrict__ d0, const float* __restrict__ d1,
            float* __restrict__ Xf, bf16* __restrict__ Yb) {
  long i = (long)blockIdx.x * 256 + threadIdx.x;
  const long stride = (long)gridDim.x * 256;
  const long n = 8L * 1024 * 512;
  for (; i < n; i += stride) {
    const int d = (int)(i & 511);
    const long nn = i >> 9;  // img*1024 + row
    const int img = (int)(nn >> 10);
    const int row = (int)(nn & 1023);
    const int b = img >> 1, s = img & 1;
    const float v = (s ? d1 : d0)[((long)b * 1024 + row) * 512 + d];
    Xf[i] = v;
    Yb[(nn << 10) + d] = __float2bfloat16(v);
  }
}

// softmax over rows of 1024 fp16 logits, in-place rewrite as bf16 probs (wave per row)
__global__ __launch_bounds__(256)
void softmax_rows(__half* S) {
  const int w = threadIdx.x >> 6, l = threadIdx.x & 63;
  const long row = (long)blockIdx.x * 4 + w;
  __half* p = S + row * 1024;
  float xs[16];
  const __half2* hp = (const __half2*)(p + l * 16);
#pragma unroll
  for (int i = 0; i < 8; i++) {
    float2 f = __half22float2(hp[i]);
    xs[2 * i] = f.x; xs[2 * i + 1] = f.y;
  }
  float mx = xs[0];
#pragma unroll
  for (int i = 1; i < 16; i++) mx = fmaxf(mx, xs[i]);
#pragma unroll
  for (int o = 32; o >= 1; o >>= 1) mx = fmaxf(mx, __shfl_xor(mx, o));
  float s = 0.f;
#pragma unroll
  for (int i = 0; i < 16; i++) { xs[i] = __expf(xs[i] - mx); s += xs[i]; }
#pragma unroll
  for (int o = 32; o >= 1; o >>= 1) s += __shfl_xor(s, o);
  const float inv = 1.f / s;
  bf16* ob = (bf16*)p;
#pragma unroll
  for (int i = 0; i < 16; i++) ob[l * 16 + i] = __float2bfloat16(xs[i] * inv);
}

// transpose [8][1024][512-cols-of-ldi] (2-byte elems) -> [8][512][1024]
__global__ __launch_bounds__(256)
void transpose_2b(const unsigned short* __restrict__ in, int ldi,
                  unsigned short* __restrict__ out) {
  __shared__ unsigned short tile[64][65];
  const int img = blockIdx.z;
  const int m0 = blockIdx.y * 64, c0 = blockIdx.x * 64;
  const int col = threadIdx.x & 63, r0 = threadIdx.x >> 6;
  const unsigned short* ip = in + ((long)img * 1024 + m0) * ldi + c0;
#pragma unroll
  for (int i = 0; i < 16; i++) { int r = r0 + i * 4; tile[r][col] = ip[(long)r * ldi + col]; }
  __syncthreads();
  unsigned short* op = out + ((long)img * 512 + c0) * 1024 + m0;
#pragma unroll
  for (int i = 0; i < 16; i++) { int r = r0 + i * 4; op[(long)r * 1024 + col] = tile[col][r]; }
}

// instance-norm stats: column sums over n per (img, channel); stats pre-zeroed
__global__ __launch_bounds__(256)
void in_stats(const float* __restrict__ T1, float* __restrict__ stats) {
  const int img = blockIdx.z;
  const int c = blockIdx.x * 256 + threadIdx.x;
  const int nb = blockIdx.y;
  const float* p = T1 + ((long)img * 1024 + nb * 128) * 1024 + c;
  float s = 0.f, s2 = 0.f;
#pragma unroll 4
  for (int i = 0; i < 128; i++) { const float x = p[(long)i * 1024]; s += x; s2 += x * x; }
  atomicAdd(&stats[img * 2048 + c], s);
  atomicAdd(&stats[img * 2048 + 1024 + c], s2);
}

__global__ __launch_bounds__(256)
void in_apply(const float* __restrict__ T1, const float* __restrict__ stats,
              bf16* __restrict__ Z) {
  long i = (long)blockIdx.x * 256 + threadIdx.x;
  const long stride = (long)gridDim.x * 256;
  for (; i < 8L * 1024 * 1024; i += stride) {
    const int c = (int)(i & 1023);
    const int img = (int)(i >> 20);
    const float mean = stats[img * 2048 + c] * (1.f / 1024.f);
    const float var = fmaxf(stats[img * 2048 + 1024 + c] * (1.f / 1024.f) - mean * mean, 0.f);
    const float zz = (T1[i] - mean) * rsqrtf(var + 1e-5f);
    Z[i] = __float2bfloat16(fmaxf(zz, 0.f));
  }
}

__global__ __launch_bounds__(256)
void fill_bins(float* C, const float* alpha) {
  const int i = blockIdx.x * 256 + threadIdx.x;
  if (i >= 4 * 1025) return;
  const float a = *alpha;
  const int b = i / 1025, n = i - b * 1025;
  C[((long)b * 1025 + n) * 1025 + 1024] = a;
  C[((long)b * 1025 + 1024) * 1025 + n] = a;
}

// fp32 coupling -> fp16 straight copy + fp16 transpose (for L2-resident sinkhorn)
__global__ __launch_bounds__(256)
void coup_to_fp16(const float* __restrict__ in, __half* __restrict__ outN,
                  __half* __restrict__ outT) {
  __shared__ float tile[32][33];
  const int b = blockIdx.z;
  const int x0 = blockIdx.x * 32, y0 = blockIdx.y * 32;
  const int lx = threadIdx.x & 31, ly = threadIdx.x >> 5;  // ly 0..7
#pragma unroll
  for (int i = 0; i < 4; i++) {
    const int y = ly + i * 8;
    if (y0 + y < 1025 && x0 + lx < 1025) {
      const float vv = in[((long)b * 1025 + y0 + y) * 1025 + x0 + lx];
      tile[y][lx] = vv;
      outN[((long)b * 1025 + y0 + y) * 1025 + x0 + lx] = __float2half(vv);
    }
  }
  __syncthreads();
#pragma unroll
  for (int i = 0; i < 4; i++) {
    const int y = ly + i * 8;
    if (x0 + y < 1025 && y0 + lx < 1025)
      outT[((long)b * 1025 + x0 + y) * 1025 + y0 + lx] = __float2half(tile[lx][y]);
  }
}

// -------- persistent Sinkhorn: 256 blocks x 1024 threads (FULL chip) --------
// Round-7 restructure (r6 counters: VALUBusy 10.4%, HBM 0.33% -> barrier/latency-bound,
// ~9.3 us/round of which ~8 us is barrier + staging latency):
//  (a) 4 independent batches -> 4 independent barrier groups of 64 blocks each, on
//      4 separate 128B-spaced LLC lines. Cuts arrival count 4x and poll contention ~8x
//      (s_sleep(2) halves poll rate; 256 pollers on ONE line was ~4 accesses/cycle at
//      a single LLC bank, queueing the fetch_adds behind poll traffic).
//  (b) Each wave's C row and CT row (static assignment) preloaded into registers ONCE
//      (+34 VGPR, ~100 total < 128 limit for 16 waves/CU). Eliminates the per-round
//      2 KB/wave L2 re-read; per-round global traffic is just the 4.1 KB u/v stage.
//  (c) Staging shrinks 4100 -> 1025 floats (per-batch slice only); LDS 16.9K -> 4.1K.
//  Row 1024 (1 wave per batch) is re-read per round: 4 KB stays L1-hot on that CU and
//  the loads hide under the wave's regular-row compute (avoids +32 VGPR on all waves).
#define SK_BLOCKS 256

#define SK_ROUND(CREG, CLAST, XROW, SRC, DST)                                   \
  {                                                                             \
    sv[t] = __hip_atomic_load(&(SRC)[t], __ATOMIC_RELAXED,                      \
                              __HIP_MEMORY_SCOPE_AGENT);                        \
    if (t == 0)                                                                 \
      sv[1024] = __hip_atomic_load(&(SRC)[1024], __ATOMIC_RELAXED,              \
                                   __HIP_MEMORY_SCOPE_AGENT);                   \
    __syncthreads();                                                            \
    float M = (l == 0) ? ((CLAST) + sv[1024]) : -3.0e38f;                       \
    const float extra = M;                                                      \
    float x[16];                                                                \
    _Pragma("unroll") for (int i = 0; i < 16; i++) {                            \
      x[i] = (CREG)[i] + sv[l + 64 * i];                                        \
      M = fmaxf(M, x[i]);                                                       \
    }                                                                           \
    _Pragma("unroll") for (int o = 32; o >= 1; o >>= 1)                         \
        M = fmaxf(M, __shfl_xor(M, o));                                         \
    float S = (l == 0) ? __expf(extra - M) : 0.f;                               \
    _Pragma("unroll") for (int i = 0; i < 16; i++) S += __expf(x[i] - M);       \
    _Pragma("unroll") for (int o = 32; o >= 1; o >>= 1) S += __shfl_xor(S, o);  \
    if (l == 0)                                                                 \
      __hip_atomic_store(&(DST)[lw], norm - (M + __logf(S)),                    \
                         __ATOMIC_RELAXED, __HIP_MEMORY_SCOPE_AGENT);           \
    if (xtra) { /* row 1024 of this batch: L1-hot per-round reload */           \
      float M2 = (l == 0) ? (__half2float((XROW)[1024]) + sv[1024]) : -3.0e38f; \
      const float e2 = M2;                                                      \
      float y[16];                                                              \
      _Pragma("unroll") for (int i = 0; i < 16; i++) {                          \
        y[i] = __half2float((XROW)[l + 64 * i]) + sv[l + 64 * i];               \
        M2 = fmaxf(M2, y[i]);                                                   \
      }                                                                         \
      _Pragma("unroll") for (int o = 32; o >= 1; o >>= 1)                       \
          M2 = fmaxf(M2, __shfl_xor(M2, o));                                    \
      float S2 = (l == 0) ? __expf(e2 - M2) : 0.f;                              \
      _Pragma("unroll") for (int i = 0; i < 16; i++) S2 += __expf(y[i] - M2);   \
      _Pragma("unroll") for (int o = 32; o >= 1; o >>= 1)                       \
          S2 += __shfl_xor(S2, o);                                              \
      if (l == 0)                                                               \
        __hip_atomic_store(&(DST)[1024], (logN + norm) - (M2 + __logf(S2)),     \
                           __ATOMIC_RELAXED, __HIP_MEMORY_SCOPE_AGENT);         \
    }                                                                           \
    __syncthreads(); /* drains AGENT stores (vmcnt) + protects sv reuse */      \
    barTarget += 64;                                                            \
    if (t == 0) {                                                               \
      __hip_atomic_fetch_add(bctr, 1u, __ATOMIC_RELEASE,                        \
                             __HIP_MEMORY_SCOPE_AGENT);                         \
      while (__hip_atomic_load(bctr, __ATOMIC_RELAXED,                          \
                               __HIP_MEMORY_SCOPE_AGENT) < barTarget)           \
        __builtin_amdgcn_s_sleep(2);                                            \
      (void)__hip_atomic_load(bctr, __ATOMIC_ACQUIRE,                           \
                              __HIP_MEMORY_SCOPE_AGENT);                        \
    }                                                                           \
    __syncthreads();                                                            \
  }

__global__ __launch_bounds__(1024)
void sinkhorn_pers(const __half* __restrict__ C, const __half* __restrict__ CT,
                   float* __restrict__ u, float* __restrict__ v,
                   unsigned int* __restrict__ ctr,
                   float norm, float logN, int iters) {
  __shared__ float sv[1028];
  const int t = threadIdx.x;
  const int w = t >> 6, l = t & 63;
  const int b = blockIdx.x >> 6;   // batch 0..3
  const int kb = blockIdx.x & 63;  // block within batch
  const int lw = kb * 16 + w;      // wave's row within batch: 0..1023
  unsigned int* bctr = ctr + b * 32;  // 4 counters, 128B apart
  const __half* Cb = C + (long)b * 1050625;
  const __half* CTb = CT + (long)b * 1050625;
  float* ub = u + b * 1025;
  float* vb = v + b * 1025;

  // one-time preload: this wave's C row (for u-update) and CT row (for v-update)
  float cr[16], cc[16];
  float clC, clT;
  {
    const __half* rc = Cb + (long)lw * 1025;
    const __half* rt = CTb + (long)lw * 1025;
#pragma unroll
    for (int i = 0; i < 16; i++) {
      cr[i] = __half2float(rc[l + 64 * i]);
      cc[i] = __half2float(rt[l + 64 * i]);
    }
    clC = (l == 0) ? __half2float(rc[1024]) : 0.f;
    clT = (l == 0) ? __half2float(rt[1024]) : 0.f;
  }
  const bool xtra = (lw == 0);  // this wave also handles row 1024 of its batch
  const __half* xrowC = Cb + (long)1024 * 1025;
  const __half* xrowT = CTb + (long)1024 * 1025;

  unsigned int barTarget = 0;
  for (int it = 0; it < iters; it++) {
    SK_ROUND(cr, clC, xrowC, vb, ub);  // u = log_mu - LSE_cols(C + v)
    SK_ROUND(cc, clT, xrowT, ub, vb);  // v = log_nu - LSE_rows(C + u) via CT
  }
}

__global__ __launch_bounds__(256)
void ot_final(float* __restrict__ C, const float* __restrict__ u,
              const float* __restrict__ v, float norm) {
  long i = (long)blockIdx.x * 256 + threadIdx.x;
  if (i >= 4L * 1025 * 1025) return;
  const int b = (int)(i / 1050625);
  const long r = i - (long)b * 1050625;
  const int n = (int)(r / 1025);
  const int m = (int)(r - (long)n * 1025);
  C[i] += u[b * 1025 + n] + v[b * 1025 + m] - norm;
}

// ---------------- host ----------------
extern "C" void kernel_launch(void* const* d_in, const int* in_sizes, int n_in,
                              void* d_out, int out_size, void* d_ws, size_t ws_size,
                              hipStream_t stream) {
  (void)in_sizes; (void)n_in; (void)out_size;
  const float* descs0 = (const float*)d_in[0];
  const float* descs1 = (const float*)d_in[1];
  const float* Wq = (const float*)d_in[2];
  const float* bq = (const float*)d_in[3];
  const float* Wk = (const float*)d_in[4];
  const float* bk = (const float*)d_in[5];
  const float* Wv = (const float*)d_in[6];
  const float* bvv = (const float*)d_in[7];
  const float* Wm = (const float*)d_in[8];
  const float* bm = (const float*)d_in[9];
  const float* W1 = (const float*)d_in[10];
  const float* b1 = (const float*)d_in[11];
  const float* W2 = (const float*)d_in[12];
  const float* b2 = (const float*)d_in[13];
  const float* Wf = (const float*)d_in[14];
  const float* bff = (const float*)d_in[15];
  const float* alpha = (const float*)d_in[16];

  char* ws = (char*)d_ws;
  size_t off = 0;
  auto alloc = [&](size_t bytes) -> void* {
    off = (off + 255) & ~(size_t)255;
    void* p = ws + off;
    off += bytes;
    return p;
  };

  // adaptive attention chunking: full scores buffer needs ~206 MB of ws
  const bool full = ws_size >= ((size_t)210 << 20);
  const int nch = full ? 1 : 4;
  const int chImgs = full ? 8 : 2;
  const size_t scrBytes = full ? ((size_t)chImgs * 8 * 1024 * 1024 * 2)  // 128 MB
                               : 50331648;                               // 48 MB

  bf16* wL = (bf16*)alloc(2621440L * 2);           // rotating per-layer weights (5 MB)
  float* bqkv = (float*)alloc(1536 * 4);
  bf16* WfB = (bf16*)alloc(512L * 512 * 2);
  float* Xf = (float*)alloc(8L * 1024 * 512 * 4);  // fp32 residual stream
  bf16* Yb = (bf16*)alloc(8L * 1024 * 1024 * 2);   // [img][n][1024]: 0:512 x, 512:1024 msg
  bf16* QKVb = (bf16*)alloc(8L * 1024 * 1536 * 2); // [token][1536] q|k|v
  bf16* vchan = (bf16*)alloc(8L * 1024 * 512 * 2); // [img][512ch][1024tok]
  bf16* Ob = (bf16*)alloc(8L * 1024 * 512 * 2);    // attn out [token][512]
  char* SCR = (char*)alloc(scrBytes);              // scores / T1+Zb / Ch+CTh+mproj
  float* stats = (float*)alloc(8L * 2048 * 4);
  float* u = (float*)alloc(4L * 1025 * 4);
  float* v = (float*)alloc(4L * 1025 * 4);
  unsigned int* ctr = (unsigned int*)alloc(512);   // 4 barrier counters, 128B apart

  bf16* wqkv = wL;                 // [1536][512]
  bf16* wm = wL + 786432;
  bf16* w1 = wL + 1048576;
  bf16* w2 = wL + 2097152;
  __half* scoresH = (__half*)SCR;  // chunk: chImgs*8*1024*1024 fp16
  bf16* probsB = (bf16*)SCR;
  float* T1 = (float*)SCR;                 // 32 MB
  bf16* Zb = (bf16*)(SCR + 33554432);      // 16 MB
  __half* Ch = (__half*)SCR;               // 8.4 MB fp16 couplings (post-layers)
  __half* CTh = (__half*)(SCR + 8405248);  // 8.4 MB fp16 transposed
  bf16* mproj = (bf16*)(SCR + 33554432);   // 8 MB (post-layers)
  float* coup = (float*)d_out;

  cvt_f2b<<<512, 256, 0, stream>>>(Wf, WfB, 512L * 512);
  init_x<<<4096, 256, 0, stream>>>(descs0, descs1, Xf, Yb);

  auto gemm = [&](int ntile, const bf16* A, const bf16* B, int M, int N, int K,
                  int lda, int ldb, long sAimg, long sAh, long sBimg, long sBh,
                  int Z, int ZH, int cross, float scale, const float* bias,
                  float* Cf, int ldcf, long sCfImg, long sCfH,
                  bf16* Cb, int ldcb, long sCbImg, long sCbH,
                  __half* Ch_, int ldch, long sChImg, long sChH,
                  const float* resid) {
    GemmP p;
    p.A = A; p.B = B; p.M = M; p.N = N; p.K = K; p.lda = lda; p.ldb = ldb;
    p.sAimg = sAimg; p.sAh = sAh; p.sBimg = sBimg; p.sBh = sBh;
    p.ZH = ZH; p.cross = cross; p.scale = scale; p.bias = bias;
    p.Cf = Cf; p.ldcf = ldcf; p.sCfImg = sCfImg; p.sCfH = sCfH;
    p.Cb = Cb; p.ldcb = ldcb; p.sCbImg = sCbImg; p.sCbH = sCbH;
    p.Ch = Ch_; p.ldch = ldch; p.sChImg = sChImg; p.sChH = sChH;
    p.resid = resid;
    dim3 g((unsigned)((N + ntile - 1) / ntile), (unsigned)((M + 127) / 128), (unsigned)Z);
    if (ntile == 128) gemm_bt<128><<<g, 256, 0, stream>>>(p);
    else gemm_bt<64><<<g, 256, 0, stream>>>(p);
  };

  for (int i = 0; i < 12; i++) {
    const int cross = i & 1;  // NAMES = self,cross,self,...
    cvt_layer<<<10247, 256, 0, stream>>>(Wq, Wk, Wv, Wm, W1, W2, bq, bk, bvv, i, wL, bqkv);

    // fused QKV: [8192,1536] = Yb[:, :512] x Wqkv^T
    gemm(128, Yb, wqkv, 8192, 1536, 512, 1024, 512, 0, 0, 0, 0, 1, 1, 0, 1.f, bqkv,
         nullptr, 0, 0, 0, QKVb, 1536, 0, 0, nullptr, 0, 0, 0, nullptr);
    // v channels -> channel-major
    transpose_2b<<<dim3(8, 16, 8), 256, 0, stream>>>((const unsigned short*)(QKVb + 1024),
                                                     1536, (unsigned short*)vchan);
    for (int c = 0; c < nch; c++) {
      const long tokOfs = (long)c * chImgs * 1024 * 1536;
      // scores[limg][h][n][m] = q.k^T / 8  (fp16)
      gemm(128, QKVb + tokOfs, QKVb + tokOfs + 512, 1024, 1024, 64, 1536, 1536,
           1572864, 64, 1572864, 64, chImgs * 8, 8, cross,
           0.125f, nullptr,
           nullptr, 0, 0, 0, nullptr, 0, 0, 0,
           scoresH, 1024, 8L * 1048576, 1048576, nullptr);
      softmax_rows<<<chImgs * 2048, 256, 0, stream>>>(scoresH);
      // O[limg][n][h*64+dh] = probs x V  (NTILE=64: no wasted MFMA on N=64)
      gemm(64, probsB, vchan + (long)c * chImgs * 524288, 1024, 64, 1024, 1024, 1024,
           8L * 1048576, 1048576, 524288, 65536, chImgs * 8, 8, cross,
           1.f, nullptr,
           nullptr, 0, 0, 0, Ob + (long)c * chImgs * 524288, 512, 524288, 64,
           nullptr, 0, 0, 0, nullptr);
    }
    // msg -> Yb[:, 512:1024]  (wm pre-permuted for head-merge order)
    gemm(128, Ob, wm, 8192, 512, 512, 512, 512, 0, 0, 0, 0, 1, 1, 0, 1.f, bm + i * 512,
         nullptr, 0, 0, 0, Yb + 512, 1024, 0, 0, nullptr, 0, 0, 0, nullptr);
    // T1 = W1 x [x; msg] + b1 (fp32)
    gemm(128, Yb, w1, 8192, 1024, 1024, 1024, 1024, 0, 0, 0, 0, 1, 1, 0, 1.f, b1 + i * 1024,
         T1, 1024, 0, 0, nullptr, 0, 0, 0, nullptr, 0, 0, 0, nullptr);
    hipMemsetAsync(stats, 0, 8L * 2048 * 4, stream);
    in_stats<<<dim3(4, 8, 8), 256, 0, stream>>>(T1, stats);
    in_apply<<<8192, 256, 0, stream>>>(T1, stats, Zb);
    // x += W2 z + b2 : fp32 residual into Xf, bf16 mirror into Yb[:, :512]
    gemm(128, Zb, w2, 8192, 512, 1024, 1024, 1024, 0, 0, 0, 0, 1, 1, 0, 1.f, b2 + i * 512,
         Xf, 512, 0, 0, Yb, 1024, 0, 0, nullptr, 0, 0, 0, Xf);
  }

  // final projection + score matrix into d_out
  gemm(128, Yb, WfB, 8192, 512, 512, 1024, 512, 0, 0, 0, 0, 1, 1, 0, 1.f, bff,
       nullptr, 0, 0, 0, mproj, 512, 0, 0, nullptr, 0, 0, 0, nullptr);
  gemm(128, mproj, mproj + 524288, 1024, 1024, 512, 512, 512,
       1048576, 0, 1048576, 0, 4, 1, 0,
       0.044194173824159216f, nullptr,
       coup, 1025, 1050625, 0, nullptr, 0, 0, 0, nullptr, 0, 0, 0, nullptr);
  fill_bins<<<17, 256, 0, stream>>>(coup, alpha);
  coup_to_fp16<<<dim3(33, 33, 4), 256, 0, stream>>>(coup, Ch, CTh);

  hipMemsetAsync(u, 0, 4L * 1025 * 4, stream);
  hipMemsetAsync(v, 0, 4L * 1025 * 4, stream);
  hipMemsetAsync(ctr, 0, 512, stream);
  const float NORM = -logf(2048.f);
  const float LOGN = logf(1024.f);
  int iters = 100;
  void* args[] = {(void*)&Ch, (void*)&CTh, (void*)&u, (void*)&v, (void*)&ctr,
                  (void*)&NORM, (void*)&LOGN, (void*)&iters};
  hipLaunchCooperativeKernel((void*)sinkhorn_pers, dim3(SK_BLOCKS), dim3(1024), args, 0, stream);
  ot_final<<<16417, 256, 0, stream>>>(coup, u, v, NORM);
}

// Round 2
// 5147.487 us; speedup vs baseline: 1.1162x; 1.0878x over previous
//
#include <hip/hip_runtime.h>
#include <hip/hip_bf16.h>
#include <hip/hip_fp16.h>
#include <cmath>

using bf16 = __hip_bfloat16;
typedef __attribute__((ext_vector_type(8))) short short8;
typedef __attribute__((ext_vector_type(4))) float floatx4;
typedef unsigned long long u64t;

__device__ __forceinline__ void lds_load16(void* lds, const void* g) {
  __builtin_amdgcn_global_load_lds(
      (const __attribute__((address_space(1))) void*)g,
      (__attribute__((address_space(3))) void*)lds, 16, 0, 0);
}

// ---------------- generic BT GEMM: C[M][N] = scale*(A[M][K] x B[N][K]^T) + bias ----------
struct GemmP {
  const bf16* A; const bf16* B;
  int M, N, K, lda, ldb;
  long sAimg, sAh, sBimg, sBh;
  int ZH, cross;
  float scale;
  const float* bias;
  float* Cf; int ldcf; long sCfImg, sCfH;
  bf16* Cb; int ldcb; long sCbImg, sCbH;
  __half* Ch; int ldch; long sChImg, sChH;
  const float* resid;  // fp32, same indexing as Cf
};

template <int NTILE>  // 128: 4 waves x (64x64); 64: 4 waves x (32x64)
__global__ __launch_bounds__(256, 2)
void gemm_bt(GemmP p) {
  __shared__ __align__(16) bf16 As[128 * 32];
  __shared__ __align__(16) bf16 Bs[NTILE * 32];
  constexpr int MI = (NTILE == 128) ? 4 : 2;
  const int z = blockIdx.z;
  const int imgA = z / p.ZH;
  const int h = z - imgA * p.ZH;
  const int imgB = imgA ^ p.cross;
  const bf16* Ab = p.A + (long)imgA * p.sAimg + (long)h * p.sAh;
  const bf16* Bb = p.B + (long)imgB * p.sBimg + (long)h * p.sBh;
  const int m0 = blockIdx.y * 128, n0 = blockIdx.x * NTILE;
  const int t = threadIdx.x, w = t >> 6, l = t & 63;
  const int lr = l >> 2, lk = (l & 3) * 8;   // staging: row-in-chunk, k-elem offset
  const int fr = l & 15, fk = (l >> 4) * 8;  // fragment: row-in-16tile, k offset

  const bf16* aG0 = Ab + (long)(m0 + w * 16 + lr) * p.lda + lk;
  const bf16* aG1 = aG0 + (long)64 * p.lda;
  const bf16* bG0 = Bb + (long)(n0 + w * 16 + lr) * p.ldb + lk;
  const bf16* bG1 = bG0 + (long)64 * p.ldb;
  bf16* aL0 = &As[w * 16 * 32];
  bf16* aL1 = &As[(w + 4) * 16 * 32];
  bf16* bL0 = &Bs[w * 16 * 32];
  bf16* bL1 = &Bs[(w + 4) * 16 * 32];
  const int wr = (NTILE == 128) ? (w >> 1) * 64 : w * 32;
  const int wc = (NTILE == 128) ? (w & 1) * 64 : 0;

  floatx4 zero4 = {0.f, 0.f, 0.f, 0.f};
  floatx4 acc[MI][4];
#pragma unroll
  for (int i = 0; i < MI; i++)
#pragma unroll
    for (int j = 0; j < 4; j++) acc[i][j] = zero4;

  for (int k0 = 0; k0 < p.K; k0 += 32) {
    lds_load16(aL0, aG0 + k0);
    lds_load16(aL1, aG1 + k0);
    lds_load16(bL0, bG0 + k0);
    if (NTILE == 128) lds_load16(bL1, bG1 + k0);
    __syncthreads();
    short8 af[MI], bfv[4];
#pragma unroll
    for (int i = 0; i < MI; i++)
      af[i] = *(const short8*)&As[(wr + i * 16 + fr) * 32 + fk];
#pragma unroll
    for (int j = 0; j < 4; j++)
      bfv[j] = *(const short8*)&Bs[(wc + j * 16 + fr) * 32 + fk];
#pragma unroll
    for (int i = 0; i < MI; i++)
#pragma unroll
      for (int j = 0; j < 4; j++)
        acc[i][j] = __builtin_amdgcn_mfma_f32_16x16x32_bf16(af[i], bfv[j], acc[i][j], 0, 0, 0);
    __syncthreads();
  }

  // epilogue: D[row][col], col = lane&15, row = (lane>>4)*4 + r  [m89-verified layout]
  const int cl = l & 15, rq = (l >> 4) * 4;
  const long cfBase = (long)imgA * p.sCfImg + (long)h * p.sCfH;
  const long cbBase = (long)imgA * p.sCbImg + (long)h * p.sCbH;
  const long chBase = (long)imgA * p.sChImg + (long)h * p.sChH;
#pragma unroll
  for (int j = 0; j < 4; j++) {
    const int col = n0 + wc + j * 16 + cl;
    if (col >= p.N) continue;
    const float bv = p.bias ? p.bias[col] : 0.f;
#pragma unroll
    for (int i = 0; i < MI; i++) {
#pragma unroll
      for (int r = 0; r < 4; r++) {
        const int row = m0 + wr + i * 16 + rq + r;
        float val = acc[i][j][r] * p.scale + bv;
        if (p.resid) val += p.resid[cfBase + (long)row * p.ldcf + col];
        if (p.Cf) p.Cf[cfBase + (long)row * p.ldcf + col] = val;
        if (p.Cb) p.Cb[cbBase + (long)row * p.ldcb + col] = __float2bfloat16(val);
        if (p.Ch) p.Ch[chBase + (long)row * p.ldch + col] = __float2half(val);
      }
    }
  }
}

// ---------------- elementwise / helper kernels ----------------
__global__ __launch_bounds__(256)
void cvt_f2b(const float* __restrict__ in, bf16* __restrict__ out, long n) {
  long i = (long)blockIdx.x * 256 + threadIdx.x;
  const long stride = (long)gridDim.x * 256;
  for (; i < n; i += stride) out[i] = __float2bfloat16(in[i]);
}

// fused per-layer weight conversion into rotating buffer (5 MB):
// [0:768K) wqkv stacked | [768K:1M) wm(col-permuted) | [1M:2M) w1 | [2M:2.5M) w2
// plus packed qkv bias (1536 floats)
__global__ __launch_bounds__(256)
void cvt_layer(const float* __restrict__ Wq, const float* __restrict__ Wk,
               const float* __restrict__ Wv, const float* __restrict__ Wm,
               const float* __restrict__ W1, const float* __restrict__ W2,
               const float* __restrict__ bq, const float* __restrict__ bk,
               const float* __restrict__ bv,
               int layer, bf16* __restrict__ out, float* __restrict__ bqkv) {
  const long i = (long)blockIdx.x * 256 + threadIdx.x;
  if (i >= 2621440L + 1536) return;
  if (i >= 2621440L) {
    const int j = (int)(i - 2621440L);
    float b;
    if (j < 512) b = bq[layer * 512 + j];
    else if (j < 1024) b = bk[layer * 512 + j - 512];
    else b = bv[layer * 512 + j - 1024];
    bqkv[j] = b;
    return;
  }
  float v;
  if (i < 262144) {
    v = Wq[(long)layer * 262144 + i];
  } else if (i < 524288) {
    v = Wk[(long)layer * 262144 + i - 262144];
  } else if (i < 786432) {
    v = Wv[(long)layer * 262144 + i - 524288];
  } else if (i < 1048576) {
    const long j = i - 786432;
    const int o = (int)(j >> 9), cp = (int)(j & 511);
    v = Wm[(long)layer * 262144 + o * 512 + (cp & 63) * 8 + (cp >> 6)];
  } else if (i < 2097152) {
    v = W1[(long)layer * 1048576 + i - 1048576];
  } else {
    v = W2[(long)layer * 524288 + i - 2097152];
  }
  out[i] = __float2bfloat16(v);
}

__global__ __launch_bounds__(256)
void init_x(const float* __restrict__ d0, const float* __restrict__ d1,
            float* __restrict__ Xf, bf16* __restrict__ Yb) {
  long i = (long)blockIdx.x * 256 + threadIdx.x;
  const long stride = (long)gridDim.x * 256;
  const long n = 8L * 1024 * 512;
  for (; i < n; i += stride) {
    const int d = (int)(i & 511);
    const long nn = i >> 9;  // img*1024 + row
    const int img = (int)(nn >> 10);
    const int row = (int)(nn & 1023);
    const int b = img >> 1, s = img & 1;
    const float v = (s ? d1 : d0)[((long)b * 1024 + row) * 512 + d];
    Xf[i] = v;
    Yb[(nn << 10) + d] = __float2bfloat16(v);
  }
}

// softmax over rows of 1024 fp16 logits, in-place rewrite as bf16 probs (wave per row)
__global__ __launch_bounds__(256)
void softmax_rows(__half* S) {
  const int w = threadIdx.x >> 6, l = threadIdx.x & 63;
  const long row = (long)blockIdx.x * 4 + w;
  __half* p = S + row * 1024;
  float xs[16];
  const __half2* hp = (const __half2*)(p + l * 16);
#pragma unroll
  for (int i = 0; i < 8; i++) {
    float2 f = __half22float2(hp[i]);
    xs[2 * i] = f.x; xs[2 * i + 1] = f.y;
  }
  float mx = xs[0];
#pragma unroll
  for (int i = 1; i < 16; i++) mx = fmaxf(mx, xs[i]);
#pragma unroll
  for (int o = 32; o >= 1; o >>= 1) mx = fmaxf(mx, __shfl_xor(mx, o));
  float s = 0.f;
#pragma unroll
  for (int i = 0; i < 16; i++) { xs[i] = __expf(xs[i] - mx); s += xs[i]; }
#pragma unroll
  for (int o = 32; o >= 1; o >>= 1) s += __shfl_xor(s, o);
  const float inv = 1.f / s;
  bf16* ob = (bf16*)p;
#pragma unroll
  for (int i = 0; i < 16; i++) ob[l * 16 + i] = __float2bfloat16(xs[i] * inv);
}

// transpose [8][1024][512-cols-of-ldi] (2-byte elems) -> [8][512][1024]
__global__ __launch_bounds__(256)
void transpose_2b(const unsigned short* __restrict__ in, int ldi,
                  unsigned short* __restrict__ out) {
  __shared__ unsigned short tile[64][65];
  const int img = blockIdx.z;
  const int m0 = blockIdx.y * 64, c0 = blockIdx.x * 64;
  const int col = threadIdx.x & 63, r0 = threadIdx.x >> 6;
  const unsigned short* ip = in + ((long)img * 1024 + m0) * ldi + c0;
#pragma unroll
  for (int i = 0; i < 16; i++) { int r = r0 + i * 4; tile[r][col] = ip[(long)r * ldi + col]; }
  __syncthreads();
  unsigned short* op = out + ((long)img * 512 + c0) * 1024 + m0;
#pragma unroll
  for (int i = 0; i < 16; i++) { int r = r0 + i * 4; op[(long)r * 1024 + col] = tile[col][r]; }
}

// instance-norm stats: column sums over n per (img, channel); stats pre-zeroed
__global__ __launch_bounds__(256)
void in_stats(const float* __restrict__ T1, float* __restrict__ stats) {
  const int img = blockIdx.z;
  const int c = blockIdx.x * 256 + threadIdx.x;
  const int nb = blockIdx.y;
  const float* p = T1 + ((long)img * 1024 + nb * 128) * 1024 + c;
  float s = 0.f, s2 = 0.f;
#pragma unroll 4
  for (int i = 0; i < 128; i++) { const float x = p[(long)i * 1024]; s += x; s2 += x * x; }
  atomicAdd(&stats[img * 2048 + c], s);
  atomicAdd(&stats[img * 2048 + 1024 + c], s2);
}

__global__ __launch_bounds__(256)
void in_apply(const float* __restrict__ T1, const float* __restrict__ stats,
              bf16* __restrict__ Z) {
  long i = (long)blockIdx.x * 256 + threadIdx.x;
  const long stride = (long)gridDim.x * 256;
  for (; i < 8L * 1024 * 1024; i += stride) {
    const int c = (int)(i & 1023);
    const int img = (int)(i >> 20);
    const float mean = stats[img * 2048 + c] * (1.f / 1024.f);
    const float var = fmaxf(stats[img * 2048 + 1024 + c] * (1.f / 1024.f) - mean * mean, 0.f);
    const float zz = (T1[i] - mean) * rsqrtf(var + 1e-5f);
    Z[i] = __float2bfloat16(fmaxf(zz, 0.f));
  }
}

__global__ __launch_bounds__(256)
void fill_bins(float* C, const float* alpha) {
  const int i = blockIdx.x * 256 + threadIdx.x;
  if (i >= 4 * 1025) return;
  const float a = *alpha;
  const int b = i / 1025, n = i - b * 1025;
  C[((long)b * 1025 + n) * 1025 + 1024] = a;
  C[((long)b * 1025 + 1024) * 1025 + n] = a;
}

// fp32 coupling -> fp16 straight copy + fp16 transpose (for L2-resident sinkhorn)
__global__ __launch_bounds__(256)
void coup_to_fp16(const float* __restrict__ in, __half* __restrict__ outN,
                  __half* __restrict__ outT) {
  __shared__ float tile[32][33];
  const int b = blockIdx.z;
  const int x0 = blockIdx.x * 32, y0 = blockIdx.y * 32;
  const int lx = threadIdx.x & 31, ly = threadIdx.x >> 5;  // ly 0..7
#pragma unroll
  for (int i = 0; i < 4; i++) {
    const int y = ly + i * 8;
    if (y0 + y < 1025 && x0 + lx < 1025) {
      const float vv = in[((long)b * 1025 + y0 + y) * 1025 + x0 + lx];
      tile[y][lx] = vv;
      outN[((long)b * 1025 + y0 + y) * 1025 + x0 + lx] = __float2half(vv);
    }
  }
  __syncthreads();
#pragma unroll
  for (int i = 0; i < 4; i++) {
    const int y = ly + i * 8;
    if (x0 + y < 1025 && y0 + lx < 1025)
      outT[((long)b * 1025 + x0 + y) * 1025 + y0 + lx] = __float2half(tile[lx][y]);
  }
}

// -------- persistent Sinkhorn: 256 blocks x 1024 threads (FULL chip) --------
// Round-8 restructure. r7 evidence: sharding the counter barrier 4x + register-resident
// C rows only moved 9.3 -> 8.9 us/round (VALUBusy still 11%) => the round cost is a
// FIXED chain of ~5 serialized agent-scope LLC round trips (result store, release RMW,
// poll detect, acquire load, u/v stage load), not contention.
// Fix: carry the synchronization IN the data. Each u/v entry is a 64-bit word
// (tag<<32 | f32bits) written by ONE relaxed 8B atomic store. Readers poll the data
// directly: load pair, stage value to LDS, loop on __syncthreads_and(tag==round).
// No counter, no fences, no separate barrier => ~2-3 LLC trips per half-round.
// Value+tag travel in one atomic object, so relaxed ordering everywhere is sufficient.
#define SK_BLOCKS 256

#define SK_ROUND(CREG, CLAST, XROW, SRC, DST)                                   \
  {                                                                             \
    /* poll+stage: retry until every entry of SRC carries the current tag */    \
    int first = 1, ok;                                                          \
    do {                                                                        \
      if (!first) __builtin_amdgcn_s_sleep(1);                                  \
      first = 0;                                                                \
      const u64t pr = __hip_atomic_load(&(SRC)[t], __ATOMIC_RELAXED,            \
                                        __HIP_MEMORY_SCOPE_AGENT);              \
      ok = ((unsigned)(pr >> 32) == tag);                                       \
      sv[t] = __uint_as_float((unsigned)pr);                                    \
      if (t == 0) {                                                             \
        const u64t qr = __hip_atomic_load(&(SRC)[1024], __ATOMIC_RELAXED,       \
                                          __HIP_MEMORY_SCOPE_AGENT);            \
        ok = ok && ((unsigned)(qr >> 32) == tag);                               \
        sv[1024] = __uint_as_float((unsigned)qr);                               \
      }                                                                         \
    } while (!__syncthreads_and(ok));                                           \
    float M = (l == 0) ? ((CLAST) + sv[1024]) : -3.0e38f;                       \
    const float extra = M;                                                      \
    float x[16];                                                                \
    _Pragma("unroll") for (int i = 0; i < 16; i++) {                            \
      x[i] = (CREG)[i] + sv[l + 64 * i];                                        \
      M = fmaxf(M, x[i]);                                                       \
    }                                                                           \
    _Pragma("unroll") for (int o = 32; o >= 1; o >>= 1)                         \
        M = fmaxf(M, __shfl_xor(M, o));                                         \
    float S = (l == 0) ? __expf(extra - M) : 0.f;                               \
    _Pragma("unroll") for (int i = 0; i < 16; i++) S += __expf(x[i] - M);       \
    _Pragma("unroll") for (int o = 32; o >= 1; o >>= 1) S += __shfl_xor(S, o);  \
    if (l == 0) {                                                               \
      const float val = norm - (M + __logf(S));                                 \
      const u64t pk = ((u64t)(tag + 1) << 32) | (u64t)__float_as_uint(val);     \
      __hip_atomic_store(&(DST)[lw], pk, __ATOMIC_RELAXED,                      \
                         __HIP_MEMORY_SCOPE_AGENT);                             \
    }                                                                           \
    if (xtra) { /* row 1024 of this batch: L1-hot per-round reload */           \
      float M2 = (l == 0) ? (__half2float((XROW)[1024]) + sv[1024]) : -3.0e38f; \
      const float e2 = M2;                                                      \
      float y[16];                                                              \
      _Pragma("unroll") for (int i = 0; i < 16; i++) {                          \
        y[i] = __half2float((XROW)[l + 64 * i]) + sv[l + 64 * i];               \
        M2 = fmaxf(M2, y[i]);                                                   \
      }                                                                         \
      _Pragma("unroll") for (int o = 32; o >= 1; o >>= 1)                       \
          M2 = fmaxf(M2, __shfl_xor(M2, o));                                    \
      float S2 = (l == 0) ? __expf(e2 - M2) : 0.f;                              \
      _Pragma("unroll") for (int i = 0; i < 16; i++) S2 += __expf(y[i] - M2);   \
      _Pragma("unroll") for (int o = 32; o >= 1; o >>= 1)                       \
          S2 += __shfl_xor(S2, o);                                              \
      if (l == 0) {                                                             \
        const float v2 = (logN + norm) - (M2 + __logf(S2));                     \
        const u64t pk2 = ((u64t)(tag + 1) << 32) | (u64t)__float_as_uint(v2);   \
        __hip_atomic_store(&(DST)[1024], pk2, __ATOMIC_RELAXED,                 \
                           __HIP_MEMORY_SCOPE_AGENT);                           \
      }                                                                         \
    }                                                                           \
    tag++;                                                                      \
    __syncthreads(); /* protect sv: next round's poll rewrites it */            \
  }

__global__ __launch_bounds__(1024)
void sinkhorn_pers(const __half* __restrict__ C, const __half* __restrict__ CT,
                   u64t* __restrict__ u, u64t* __restrict__ v,
                   float norm, float logN, int iters) {
  __shared__ float sv[1025];
  const int t = threadIdx.x;
  const int w = t >> 6, l = t & 63;
  const int b = blockIdx.x >> 6;   // batch 0..3
  const int kb = blockIdx.x & 63;  // block within batch
  const int lw = kb * 16 + w;      // wave's row within batch: 0..1023
  const __half* Cb = C + (long)b * 1050625;
  const __half* CTb = CT + (long)b * 1050625;
  u64t* ub = u + b * 1025;
  u64t* vb = v + b * 1025;

  // one-time preload: this wave's C row (for u-update) and CT row (for v-update)
  float cr[16], cc[16];
  float clC, clT;
  {
    const __half* rc = Cb + (long)lw * 1025;
    const __half* rt = CTb + (long)lw * 1025;
#pragma unroll
    for (int i = 0; i < 16; i++) {
      cr[i] = __half2float(rc[l + 64 * i]);
      cc[i] = __half2float(rt[l + 64 * i]);
    }
    clC = (l == 0) ? __half2float(rc[1024]) : 0.f;
    clT = (l == 0) ? __half2float(rt[1024]) : 0.f;
  }
  const bool xtra = (lw == 0);  // this wave also handles row 1024 of its batch
  const __half* xrowC = Cb + (long)1024 * 1025;
  const __half* xrowT = CTb + (long)1024 * 1025;

  // tag protocol: initial u/v arrays are all-zero => (tag=0, value=0.0f).
  // half 0 of iter k reads tag 2k, writes tag 2k+1; half 1 reads 2k+1, writes 2k+2.
  unsigned tag = 0;
  for (int it = 0; it < iters; it++) {
    SK_ROUND(cr, clC, xrowC, vb, ub);  // u = log_mu - LSE_cols(C + v)
    SK_ROUND(cc, clT, xrowT, ub, vb);  // v = log_nu - LSE_rows(C + u) via CT
  }
}

__global__ __launch_bounds__(256)
void ot_final(float* __restrict__ C, const u64t* __restrict__ u,
              const u64t* __restrict__ v, float norm) {
  long i = (long)blockIdx.x * 256 + threadIdx.x;
  if (i >= 4L * 1025 * 1025) return;
  const int b = (int)(i / 1050625);
  const long r = i - (long)b * 1050625;
  const int n = (int)(r / 1025);
  const int m = (int)(r - (long)n * 1025);
  const float uu = __uint_as_float((unsigned)u[b * 1025 + n]);
  const float vv = __uint_as_float((unsigned)v[b * 1025 + m]);
  C[i] += uu + vv - norm;
}

// ---------------- host ----------------
extern "C" void kernel_launch(void* const* d_in, const int* in_sizes, int n_in,
                              void* d_out, int out_size, void* d_ws, size_t ws_size,
                              hipStream_t stream) {
  (void)in_sizes; (void)n_in; (void)out_size;
  const float* descs0 = (const float*)d_in[0];
  const float* descs1 = (const float*)d_in[1];
  const float* Wq = (const float*)d_in[2];
  const float* bq = (const float*)d_in[3];
  const float* Wk = (const float*)d_in[4];
  const float* bk = (const float*)d_in[5];
  const float* Wv = (const float*)d_in[6];
  const float* bvv = (const float*)d_in[7];
  const float* Wm = (const float*)d_in[8];
  const float* bm = (const float*)d_in[9];
  const float* W1 = (const float*)d_in[10];
  const float* b1 = (const float*)d_in[11];
  const float* W2 = (const float*)d_in[12];
  const float* b2 = (const float*)d_in[13];
  const float* Wf = (const float*)d_in[14];
  const float* bff = (const float*)d_in[15];
  const float* alpha = (const float*)d_in[16];

  char* ws = (char*)d_ws;
  size_t off = 0;
  auto alloc = [&](size_t bytes) -> void* {
    off = (off + 255) & ~(size_t)255;
    void* p = ws + off;
    off += bytes;
    return p;
  };

  // adaptive attention chunking: full scores buffer needs ~206 MB of ws
  const bool full = ws_size >= ((size_t)210 << 20);
  const int nch = full ? 1 : 4;
  const int chImgs = full ? 8 : 2;
  const size_t scrBytes = full ? ((size_t)chImgs * 8 * 1024 * 1024 * 2)  // 128 MB
                               : 50331648;                               // 48 MB

  bf16* wL = (bf16*)alloc(2621440L * 2);           // rotating per-layer weights (5 MB)
  float* bqkv = (float*)alloc(1536 * 4);
  bf16* WfB = (bf16*)alloc(512L * 512 * 2);
  float* Xf = (float*)alloc(8L * 1024 * 512 * 4);  // fp32 residual stream
  bf16* Yb = (bf16*)alloc(8L * 1024 * 1024 * 2);   // [img][n][1024]: 0:512 x, 512:1024 msg
  bf16* QKVb = (bf16*)alloc(8L * 1024 * 1536 * 2); // [token][1536] q|k|v
  bf16* vchan = (bf16*)alloc(8L * 1024 * 512 * 2); // [img][512ch][1024tok]
  bf16* Ob = (bf16*)alloc(8L * 1024 * 512 * 2);    // attn out [token][512]
  char* SCR = (char*)alloc(scrBytes);              // scores / T1+Zb / Ch+CTh+mproj
  float* stats = (float*)alloc(8L * 2048 * 4);
  u64t* u = (u64t*)alloc(4L * 1025 * 8);           // (tag<<32 | f32) pairs
  u64t* v = (u64t*)alloc(4L * 1025 * 8);

  bf16* wqkv = wL;                 // [1536][512]
  bf16* wm = wL + 786432;
  bf16* w1 = wL + 1048576;
  bf16* w2 = wL + 2097152;
  __half* scoresH = (__half*)SCR;  // chunk: chImgs*8*1024*1024 fp16
  bf16* probsB = (bf16*)SCR;
  float* T1 = (float*)SCR;                 // 32 MB
  bf16* Zb = (bf16*)(SCR + 33554432);      // 16 MB
  __half* Ch = (__half*)SCR;               // 8.4 MB fp16 couplings (post-layers)
  __half* CTh = (__half*)(SCR + 8405248);  // 8.4 MB fp16 transposed
  bf16* mproj = (bf16*)(SCR + 33554432);   // 8 MB (post-layers)
  float* coup = (float*)d_out;

  cvt_f2b<<<512, 256, 0, stream>>>(Wf, WfB, 512L * 512);
  init_x<<<4096, 256, 0, stream>>>(descs0, descs1, Xf, Yb);

  auto gemm = [&](int ntile, const bf16* A, const bf16* B, int M, int N, int K,
                  int lda, int ldb, long sAimg, long sAh, long sBimg, long sBh,
                  int Z, int ZH, int cross, float scale, const float* bias,
                  float* Cf, int ldcf, long sCfImg, long sCfH,
                  bf16* Cb, int ldcb, long sCbImg, long sCbH,
                  __half* Ch_, int ldch, long sChImg, long sChH,
                  const float* resid) {
    GemmP p;
    p.A = A; p.B = B; p.M = M; p.N = N; p.K = K; p.lda = lda; p.ldb = ldb;
    p.sAimg = sAimg; p.sAh = sAh; p.sBimg = sBimg; p.sBh = sBh;
    p.ZH = ZH; p.cross = cross; p.scale = scale; p.bias = bias;
    p.Cf = Cf; p.ldcf = ldcf; p.sCfImg = sCfImg; p.sCfH = sCfH;
    p.Cb = Cb; p.ldcb = ldcb; p.sCbImg = sCbImg; p.sCbH = sCbH;
    p.Ch = Ch_; p.ldch = ldch; p.sChImg = sChImg; p.sChH = sChH;
    p.resid = resid;
    dim3 g((unsigned)((N + ntile - 1) / ntile), (unsigned)((M + 127) / 128), (unsigned)Z);
    if (ntile == 128) gemm_bt<128><<<g, 256, 0, stream>>>(p);
    else gemm_bt<64><<<g, 256, 0, stream>>>(p);
  };

  for (int i = 0; i < 12; i++) {
    const int cross = i & 1;  // NAMES = self,cross,self,...
    cvt_layer<<<10247, 256, 0, stream>>>(Wq, Wk, Wv, Wm, W1, W2, bq, bk, bvv, i, wL, bqkv);

    // fused QKV: [8192,1536] = Yb[:, :512] x Wqkv^T
    gemm(128, Yb, wqkv, 8192, 1536, 512, 1024, 512, 0, 0, 0, 0, 1, 1, 0, 1.f, bqkv,
         nullptr, 0, 0, 0, QKVb, 1536, 0, 0, nullptr, 0, 0, 0, nullptr);
    // v channels -> channel-major
    transpose_2b<<<dim3(8, 16, 8), 256, 0, stream>>>((const unsigned short*)(QKVb + 1024),
                                                     1536, (unsigned short*)vchan);
    for (int c = 0; c < nch; c++) {
      const long tokOfs = (long)c * chImgs * 1024 * 1536;
      // scores[limg][h][n][m] = q.k^T / 8  (fp16)
      gemm(128, QKVb + tokOfs, QKVb + tokOfs + 512, 1024, 1024, 64, 1536, 1536,
           1572864, 64, 1572864, 64, chImgs * 8, 8, cross,
           0.125f, nullptr,
           nullptr, 0, 0, 0, nullptr, 0, 0, 0,
           scoresH, 1024, 8L * 1048576, 1048576, nullptr);
      softmax_rows<<<chImgs * 2048, 256, 0, stream>>>(scoresH);
      // O[limg][n][h*64+dh] = probs x V  (NTILE=64: no wasted MFMA on N=64)
      gemm(64, probsB, vchan + (long)c * chImgs * 524288, 1024, 64, 1024, 1024, 1024,
           8L * 1048576, 1048576, 524288, 65536, chImgs * 8, 8, cross,
           1.f, nullptr,
           nullptr, 0, 0, 0, Ob + (long)c * chImgs * 524288, 512, 524288, 64,
           nullptr, 0, 0, 0, nullptr);
    }
    // msg -> Yb[:, 512:1024]  (wm pre-permuted for head-merge order)
    gemm(128, Ob, wm, 8192, 512, 512, 512, 512, 0, 0, 0, 0, 1, 1, 0, 1.f, bm + i * 512,
         nullptr, 0, 0, 0, Yb + 512, 1024, 0, 0, nullptr, 0, 0, 0, nullptr);
    // T1 = W1 x [x; msg] + b1 (fp32)
    gemm(128, Yb, w1, 8192, 1024, 1024, 1024, 1024, 0, 0, 0, 0, 1, 1, 0, 1.f, b1 + i * 1024,
         T1, 1024, 0, 0, nullptr, 0, 0, 0, nullptr, 0, 0, 0, nullptr);
    hipMemsetAsync(stats, 0, 8L * 2048 * 4, stream);
    in_stats<<<dim3(4, 8, 8), 256, 0, stream>>>(T1, stats);
    in_apply<<<8192, 256, 0, stream>>>(T1, stats, Zb);
    // x += W2 z + b2 : fp32 residual into Xf, bf16 mirror into Yb[:, :512]
    gemm(128, Zb, w2, 8192, 512, 1024, 1024, 1024, 0, 0, 0, 0, 1, 1, 0, 1.f, b2 + i * 512,
         Xf, 512, 0, 0, Yb, 1024, 0, 0, nullptr, 0, 0, 0, Xf);
  }

  // final projection + score matrix into d_out
  gemm(128, Yb, WfB, 8192, 512, 512, 1024, 512, 0, 0, 0, 0, 1, 1, 0, 1.f, bff,
       nullptr, 0, 0, 0, mproj, 512, 0, 0, nullptr, 0, 0, 0, nullptr);
  gemm(128, mproj, mproj + 524288, 1024, 1024, 512, 512, 512,
       1048576, 0, 1048576, 0, 4, 1, 0,
       0.044194173824159216f, nullptr,
       coup, 1025, 1050625, 0, nullptr, 0, 0, 0, nullptr, 0, 0, 0, nullptr);
  fill_bins<<<17, 256, 0, stream>>>(coup, alpha);
  coup_to_fp16<<<dim3(33, 33, 4), 256, 0, stream>>>(coup, Ch, CTh);

  hipMemsetAsync(u, 0, 4L * 1025 * 8, stream);
  hipMemsetAsync(v, 0, 4L * 1025 * 8, stream);
  const float NORM = -logf(2048.f);
  const float LOGN = logf(1024.f);
  int iters = 100;
  void* args[] = {(void*)&Ch, (void*)&CTh, (void*)&u, (void*)&v,
                  (void*)&NORM, (void*)&LOGN, (void*)&iters};
  hipLaunchCooperativeKernel((void*)sinkhorn_pers, dim3(SK_BLOCKS), dim3(1024), args, 0, stream);
  ot_final<<<16417, 256, 0, stream>>>(coup, u, v, NORM);
}

// Round 3
// 4659.601 us; speedup vs baseline: 1.2331x; 1.1047x over previous
//
#include <hip/hip_runtime.h>
#include <hip/hip_bf16.h>
#include <hip/hip_fp16.h>
#include <cmath>

using bf16 = __hip_bfloat16;
typedef __attribute__((ext_vector_type(8))) short short8;
typedef __attribute__((ext_vector_type(4))) float floatx4;
typedef unsigned long long u64t;

__device__ __forceinline__ void lds_load16(void* lds, const void* g) {
  __builtin_amdgcn_global_load_lds(
      (const __attribute__((address_space(1))) void*)g,
      (__attribute__((address_space(3))) void*)lds, 16, 0, 0);
}

// ---------------- generic BT GEMM: C[M][N] = scale*(A[M][K] x B[N][K]^T) + bias ----------
struct GemmP {
  const bf16* A; const bf16* B;
  int M, N, K, lda, ldb;
  long sAimg, sAh, sBimg, sBh;
  int ZH, cross;
  float scale;
  const float* bias;
  float* Cf; int ldcf; long sCfImg, sCfH;
  bf16* Cb; int ldcb; long sCbImg, sCbH;
  __half* Ch; int ldch; long sChImg, sChH;
  const float* resid;  // fp32, same indexing as Cf
};

template <int NTILE>  // 128: 4 waves x (64x64); 64: 4 waves x (32x64)
__global__ __launch_bounds__(256, 2)
void gemm_bt(GemmP p) {
  __shared__ __align__(16) bf16 As[128 * 32];
  __shared__ __align__(16) bf16 Bs[NTILE * 32];
  constexpr int MI = (NTILE == 128) ? 4 : 2;
  const int z = blockIdx.z;
  const int imgA = z / p.ZH;
  const int h = z - imgA * p.ZH;
  const int imgB = imgA ^ p.cross;
  const bf16* Ab = p.A + (long)imgA * p.sAimg + (long)h * p.sAh;
  const bf16* Bb = p.B + (long)imgB * p.sBimg + (long)h * p.sBh;
  const int m0 = blockIdx.y * 128, n0 = blockIdx.x * NTILE;
  const int t = threadIdx.x, w = t >> 6, l = t & 63;
  const int lr = l >> 2, lk = (l & 3) * 8;   // staging: row-in-chunk, k-elem offset
  const int fr = l & 15, fk = (l >> 4) * 8;  // fragment: row-in-16tile, k offset

  const bf16* aG0 = Ab + (long)(m0 + w * 16 + lr) * p.lda + lk;
  const bf16* aG1 = aG0 + (long)64 * p.lda;
  const bf16* bG0 = Bb + (long)(n0 + w * 16 + lr) * p.ldb + lk;
  const bf16* bG1 = bG0 + (long)64 * p.ldb;
  bf16* aL0 = &As[w * 16 * 32];
  bf16* aL1 = &As[(w + 4) * 16 * 32];
  bf16* bL0 = &Bs[w * 16 * 32];
  bf16* bL1 = &Bs[(w + 4) * 16 * 32];
  const int wr = (NTILE == 128) ? (w >> 1) * 64 : w * 32;
  const int wc = (NTILE == 128) ? (w & 1) * 64 : 0;

  floatx4 zero4 = {0.f, 0.f, 0.f, 0.f};
  floatx4 acc[MI][4];
#pragma unroll
  for (int i = 0; i < MI; i++)
#pragma unroll
    for (int j = 0; j < 4; j++) acc[i][j] = zero4;

  for (int k0 = 0; k0 < p.K; k0 += 32) {
    lds_load16(aL0, aG0 + k0);
    lds_load16(aL1, aG1 + k0);
    lds_load16(bL0, bG0 + k0);
    if (NTILE == 128) lds_load16(bL1, bG1 + k0);
    __syncthreads();
    short8 af[MI], bfv[4];
#pragma unroll
    for (int i = 0; i < MI; i++)
      af[i] = *(const short8*)&As[(wr + i * 16 + fr) * 32 + fk];
#pragma unroll
    for (int j = 0; j < 4; j++)
      bfv[j] = *(const short8*)&Bs[(wc + j * 16 + fr) * 32 + fk];
#pragma unroll
    for (int i = 0; i < MI; i++)
#pragma unroll
      for (int j = 0; j < 4; j++)
        acc[i][j] = __builtin_amdgcn_mfma_f32_16x16x32_bf16(af[i], bfv[j], acc[i][j], 0, 0, 0);
    __syncthreads();
  }

  // epilogue: D[row][col], col = lane&15, row = (lane>>4)*4 + r  [m89-verified layout]
  const int cl = l & 15, rq = (l >> 4) * 4;
  const long cfBase = (long)imgA * p.sCfImg + (long)h * p.sCfH;
  const long cbBase = (long)imgA * p.sCbImg + (long)h * p.sCbH;
  const long chBase = (long)imgA * p.sChImg + (long)h * p.sChH;
#pragma unroll
  for (int j = 0; j < 4; j++) {
    const int col = n0 + wc + j * 16 + cl;
    if (col >= p.N) continue;
    const float bv = p.bias ? p.bias[col] : 0.f;
#pragma unroll
    for (int i = 0; i < MI; i++) {
#pragma unroll
      for (int r = 0; r < 4; r++) {
        const int row = m0 + wr + i * 16 + rq + r;
        float val = acc[i][j][r] * p.scale + bv;
        if (p.resid) val += p.resid[cfBase + (long)row * p.ldcf + col];
        if (p.Cf) p.Cf[cfBase + (long)row * p.ldcf + col] = val;
        if (p.Cb) p.Cb[cbBase + (long)row * p.ldcb + col] = __float2bfloat16(val);
        if (p.Ch) p.Ch[chBase + (long)row * p.ldch + col] = __float2half(val);
      }
    }
  }
}

// ---------------- elementwise / helper kernels ----------------
__global__ __launch_bounds__(256)
void cvt_f2b(const float* __restrict__ in, bf16* __restrict__ out, long n) {
  long i = (long)blockIdx.x * 256 + threadIdx.x;
  const long stride = (long)gridDim.x * 256;
  for (; i < n; i += stride) out[i] = __float2bfloat16(in[i]);
}

// fused per-layer weight conversion into rotating buffer (5 MB):
// [0:768K) wqkv stacked | [768K:1M) wm(col-permuted) | [1M:2M) w1 | [2M:2.5M) w2
// plus packed qkv bias (1536 floats)
__global__ __launch_bounds__(256)
void cvt_layer(const float* __restrict__ Wq, const float* __restrict__ Wk,
               const float* __restrict__ Wv, const float* __restrict__ Wm,
               const float* __restrict__ W1, const float* __restrict__ W2,
               const float* __restrict__ bq, const float* __restrict__ bk,
               const float* __restrict__ bv,
               int layer, bf16* __restrict__ out, float* __restrict__ bqkv) {
  const long i = (long)blockIdx.x * 256 + threadIdx.x;
  if (i >= 2621440L + 1536) return;
  if (i >= 2621440L) {
    const int j = (int)(i - 2621440L);
    float b;
    if (j < 512) b = bq[layer * 512 + j];
    else if (j < 1024) b = bk[layer * 512 + j - 512];
    else b = bv[layer * 512 + j - 1024];
    bqkv[j] = b;
    return;
  }
  float v;
  if (i < 262144) {
    v = Wq[(long)layer * 262144 + i];
  } else if (i < 524288) {
    v = Wk[(long)layer * 262144 + i - 262144];
  } else if (i < 786432) {
    v = Wv[(long)layer * 262144 + i - 524288];
  } else if (i < 1048576) {
    const long j = i - 786432;
    const int o = (int)(j >> 9), cp = (int)(j & 511);
    v = Wm[(long)layer * 262144 + o * 512 + (cp & 63) * 8 + (cp >> 6)];
  } else if (i < 2097152) {
    v = W1[(long)layer * 1048576 + i - 1048576];
  } else {
    v = W2[(long)layer * 524288 + i - 2097152];
  }
  out[i] = __float2bfloat16(v);
}

__global__ __launch_bounds__(256)
void init_x(const float* __restrict__ d0, const float* __restrict__ d1,
            float* __restrict__ Xf, bf16* __restrict__ Yb) {
  long i = (long)blockIdx.x * 256 + threadIdx.x;
  const long stride = (long)gridDim.x * 256;
  const long n = 8L * 1024 * 512;
  for (; i < n; i += stride) {
    const int d = (int)(i & 511);
    const long nn = i >> 9;  // img*1024 + row
    const int img = (int)(nn >> 10);
    const int row = (int)(nn & 1023);
    const int b = img >> 1, s = img & 1;
    const float v = (s ? d1 : d0)[((long)b * 1024 + row) * 512 + d];
    Xf[i] = v;
    Yb[(nn << 10) + d] = __float2bfloat16(v);
  }
}

// softmax over rows of 1024 fp16 logits, in-place rewrite as bf16 probs (wave per row)
__global__ __launch_bounds__(256)
void softmax_rows(__half* S) {
  const int w = threadIdx.x >> 6, l = threadIdx.x & 63;
  const long row = (long)blockIdx.x * 4 + w;
  __half* p = S + row * 1024;
  float xs[16];
  const __half2* hp = (const __half2*)(p + l * 16);
#pragma unroll
  for (int i = 0; i < 8; i++) {
    float2 f = __half22float2(hp[i]);
    xs[2 * i] = f.x; xs[2 * i + 1] = f.y;
  }
  float mx = xs[0];
#pragma unroll
  for (int i = 1; i < 16; i++) mx = fmaxf(mx, xs[i]);
#pragma unroll
  for (int o = 32; o >= 1; o >>= 1) mx = fmaxf(mx, __shfl_xor(mx, o));
  float s = 0.f;
#pragma unroll
  for (int i = 0; i < 16; i++) { xs[i] = __expf(xs[i] - mx); s += xs[i]; }
#pragma unroll
  for (int o = 32; o >= 1; o >>= 1) s += __shfl_xor(s, o);
  const float inv = 1.f / s;
  bf16* ob = (bf16*)p;
#pragma unroll
  for (int i = 0; i < 16; i++) ob[l * 16 + i] = __float2bfloat16(xs[i] * inv);
}

// transpose [8][1024][512-cols-of-ldi] (2-byte elems) -> [8][512][1024]
__global__ __launch_bounds__(256)
void transpose_2b(const unsigned short* __restrict__ in, int ldi,
                  unsigned short* __restrict__ out) {
  __shared__ unsigned short tile[64][65];
  const int img = blockIdx.z;
  const int m0 = blockIdx.y * 64, c0 = blockIdx.x * 64;
  const int col = threadIdx.x & 63, r0 = threadIdx.x >> 6;
  const unsigned short* ip = in + ((long)img * 1024 + m0) * ldi + c0;
#pragma unroll
  for (int i = 0; i < 16; i++) { int r = r0 + i * 4; tile[r][col] = ip[(long)r * ldi + col]; }
  __syncthreads();
  unsigned short* op = out + ((long)img * 512 + c0) * 1024 + m0;
#pragma unroll
  for (int i = 0; i < 16; i++) { int r = r0 + i * 4; op[(long)r * 1024 + col] = tile[col][r]; }
}

// instance-norm stats: column sums over n per (img, channel); stats pre-zeroed
__global__ __launch_bounds__(256)
void in_stats(const float* __restrict__ T1, float* __restrict__ stats) {
  const int img = blockIdx.z;
  const int c = blockIdx.x * 256 + threadIdx.x;
  const int nb = blockIdx.y;
  const float* p = T1 + ((long)img * 1024 + nb * 128) * 1024 + c;
  float s = 0.f, s2 = 0.f;
#pragma unroll 4
  for (int i = 0; i < 128; i++) { const float x = p[(long)i * 1024]; s += x; s2 += x * x; }
  atomicAdd(&stats[img * 2048 + c], s);
  atomicAdd(&stats[img * 2048 + 1024 + c], s2);
}

__global__ __launch_bounds__(256)
void in_apply(const float* __restrict__ T1, const float* __restrict__ stats,
              bf16* __restrict__ Z) {
  long i = (long)blockIdx.x * 256 + threadIdx.x;
  const long stride = (long)gridDim.x * 256;
  for (; i < 8L * 1024 * 1024; i += stride) {
    const int c = (int)(i & 1023);
    const int img = (int)(i >> 20);
    const float mean = stats[img * 2048 + c] * (1.f / 1024.f);
    const float var = fmaxf(stats[img * 2048 + 1024 + c] * (1.f / 1024.f) - mean * mean, 0.f);
    const float zz = (T1[i] - mean) * rsqrtf(var + 1e-5f);
    Z[i] = __float2bfloat16(fmaxf(zz, 0.f));
  }
}

__global__ __launch_bounds__(256)
void fill_bins(float* C, const float* alpha) {
  const int i = blockIdx.x * 256 + threadIdx.x;
  if (i >= 4 * 1025) return;
  const float a = *alpha;
  const int b = i / 1025, n = i - b * 1025;
  C[((long)b * 1025 + n) * 1025 + 1024] = a;
  C[((long)b * 1025 + 1024) * 1025 + n] = a;
}

// fp32 coupling -> fp16 straight copy + fp16 transpose (for L2-resident sinkhorn)
__global__ __launch_bounds__(256)
void coup_to_fp16(const float* __restrict__ in, __half* __restrict__ outN,
                  __half* __restrict__ outT) {
  __shared__ float tile[32][33];
  const int b = blockIdx.z;
  const int x0 = blockIdx.x * 32, y0 = blockIdx.y * 32;
  const int lx = threadIdx.x & 31, ly = threadIdx.x >> 5;  // ly 0..7
#pragma unroll
  for (int i = 0; i < 4; i++) {
    const int y = ly + i * 8;
    if (y0 + y < 1025 && x0 + lx < 1025) {
      const float vv = in[((long)b * 1025 + y0 + y) * 1025 + x0 + lx];
      tile[y][lx] = vv;
      outN[((long)b * 1025 + y0 + y) * 1025 + x0 + lx] = __float2half(vv);
    }
  }
  __syncthreads();
#pragma unroll
  for (int i = 0; i < 4; i++) {
    const int y = ly + i * 8;
    if (x0 + y < 1025 && y0 + lx < 1025)
      outT[((long)b * 1025 + x0 + y) * 1025 + y0 + lx] = __float2half(tile[lx][y]);
  }
}

// -------- persistent Sinkhorn: 256 blocks x 1024 threads (FULL chip) --------
// Round-9. r8 evidence: data-carried sync (tag|value u64) cut 8.9 -> 6.4 us/half-round
// but FETCH_SIZE rose to 70MB: the block-wide retry loop (all 1024 threads reload all
// 1025 entries + __syncthreads_and per lap, ~0.5us/lap) multiplies the cost of ONE late
// entry. Entry 1024 is systematically last (its wave does 2 serial LSEs + a global
// re-read each round).
// Fix: (a) PER-LANE SPIN: each thread spins only on its own entry, writes LDS once,
// then a single barrier. Finished lanes are exec-masked off => no redundant reloads,
// detection = entry visibility + <=1 load latency. (b) registerize row 1024 for the
// xtra wave (drops the per-round global re-read from the chip-critical path).
#define SK_BLOCKS 256

#define SK_ROUND(CREG, CLAST, XREG, XLAST, SRC, DST)                            \
  {                                                                             \
    /* per-lane spin: wait for my entry to carry the current tag */             \
    u64t pr;                                                                    \
    while ((unsigned)((pr = __hip_atomic_load(&(SRC)[t], __ATOMIC_RELAXED,      \
                                              __HIP_MEMORY_SCOPE_AGENT)) >>    \
                      32) != tag)                                               \
      __builtin_amdgcn_s_sleep(1);                                              \
    sv[t] = __uint_as_float((unsigned)pr);                                      \
    if (t == 0) {                                                               \
      u64t qr;                                                                  \
      while ((unsigned)((qr = __hip_atomic_load(&(SRC)[1024], __ATOMIC_RELAXED, \
                                                __HIP_MEMORY_SCOPE_AGENT)) >>  \
                        32) != tag)                                             \
        __builtin_amdgcn_s_sleep(1);                                            \
      sv[1024] = __uint_as_float((unsigned)qr);                                 \
    }                                                                           \
    __syncthreads();                                                            \
    float M = (l == 0) ? ((CLAST) + sv[1024]) : -3.0e38f;                       \
    const float extra = M;                                                      \
    float x[16];                                                                \
    _Pragma("unroll") for (int i = 0; i < 16; i++) {                            \
      x[i] = (CREG)[i] + sv[l + 64 * i];                                        \
      M = fmaxf(M, x[i]);                                                       \
    }                                                                           \
    _Pragma("unroll") for (int o = 32; o >= 1; o >>= 1)                         \
        M = fmaxf(M, __shfl_xor(M, o));                                         \
    float S = (l == 0) ? __expf(extra - M) : 0.f;                               \
    _Pragma("unroll") for (int i = 0; i < 16; i++) S += __expf(x[i] - M);       \
    _Pragma("unroll") for (int o = 32; o >= 1; o >>= 1) S += __shfl_xor(S, o);  \
    if (l == 0) {                                                               \
      const float val = norm - (M + __logf(S));                                 \
      const u64t pk = ((u64t)(tag + 1) << 32) | (u64t)__float_as_uint(val);     \
      __hip_atomic_store(&(DST)[lw], pk, __ATOMIC_RELAXED,                      \
                         __HIP_MEMORY_SCOPE_AGENT);                             \
    }                                                                           \
    if (xtra) { /* row 1024 of this batch: register-resident */                 \
      float M2 = (l == 0) ? ((XLAST) + sv[1024]) : -3.0e38f;                    \
      const float e2 = M2;                                                      \
      float y[16];                                                              \
      _Pragma("unroll") for (int i = 0; i < 16; i++) {                          \
        y[i] = (XREG)[i] + sv[l + 64 * i];                                      \
        M2 = fmaxf(M2, y[i]);                                                   \
      }                                                                         \
      _Pragma("unroll") for (int o = 32; o >= 1; o >>= 1)                       \
          M2 = fmaxf(M2, __shfl_xor(M2, o));                                    \
      float S2 = (l == 0) ? __expf(e2 - M2) : 0.f;                              \
      _Pragma("unroll") for (int i = 0; i < 16; i++) S2 += __expf(y[i] - M2);   \
      _Pragma("unroll") for (int o = 32; o >= 1; o >>= 1)                       \
          S2 += __shfl_xor(S2, o);                                              \
      if (l == 0) {                                                             \
        const float v2 = (logN + norm) - (M2 + __logf(S2));                     \
        const u64t pk2 = ((u64t)(tag + 1) << 32) | (u64t)__float_as_uint(v2);   \
        __hip_atomic_store(&(DST)[1024], pk2, __ATOMIC_RELAXED,                 \
                           __HIP_MEMORY_SCOPE_AGENT);                           \
      }                                                                         \
    }                                                                           \
    tag++;                                                                      \
    __syncthreads(); /* protect sv: next round's spin rewrites it */            \
  }

__global__ __launch_bounds__(1024)
void sinkhorn_pers(const __half* __restrict__ C, const __half* __restrict__ CT,
                   u64t* __restrict__ u, u64t* __restrict__ v,
                   float norm, float logN, int iters) {
  __shared__ float sv[1025];
  const int t = threadIdx.x;
  const int w = t >> 6, l = t & 63;
  const int b = blockIdx.x >> 6;   // batch 0..3
  const int kb = blockIdx.x & 63;  // block within batch
  const int lw = kb * 16 + w;      // wave's row within batch: 0..1023
  const __half* Cb = C + (long)b * 1050625;
  const __half* CTb = CT + (long)b * 1050625;
  u64t* ub = u + b * 1025;
  u64t* vb = v + b * 1025;

  // one-time preload: this wave's C row (for u-update) and CT row (for v-update)
  float cr[16], cc[16];
  float clC, clT;
  {
    const __half* rc = Cb + (long)lw * 1025;
    const __half* rt = CTb + (long)lw * 1025;
#pragma unroll
    for (int i = 0; i < 16; i++) {
      cr[i] = __half2float(rc[l + 64 * i]);
      cc[i] = __half2float(rt[l + 64 * i]);
    }
    clC = (l == 0) ? __half2float(rc[1024]) : 0.f;
    clT = (l == 0) ? __half2float(rt[1024]) : 0.f;
  }
  const bool xtra = (lw == 0);  // this wave also handles row 1024 of its batch
  // registerized extra row (row 1024 of C and CT) for the xtra wave
  float xrC[16], xrT[16], xlC = 0.f, xlT = 0.f;
  if (xtra) {
    const __half* rc = Cb + (long)1024 * 1025;
    const __half* rt = CTb + (long)1024 * 1025;
#pragma unroll
    for (int i = 0; i < 16; i++) {
      xrC[i] = __half2float(rc[l + 64 * i]);
      xrT[i] = __half2float(rt[l + 64 * i]);
    }
    if (l == 0) {
      xlC = __half2float(rc[1024]);
      xlT = __half2float(rt[1024]);
    }
  }

  // tag protocol: initial u/v arrays are all-zero => (tag=0, value=0.0f).
  // half 0 of iter k reads tag 2k, writes tag 2k+1; half 1 reads 2k+1, writes 2k+2.
  unsigned tag = 0;
  for (int it = 0; it < iters; it++) {
    SK_ROUND(cr, clC, xrC, xlC, vb, ub);  // u = log_mu - LSE_cols(C + v)
    SK_ROUND(cc, clT, xrT, xlT, ub, vb);  // v = log_nu - LSE_rows(C + u) via CT
  }
}

__global__ __launch_bounds__(256)
void ot_final(float* __restrict__ C, const u64t* __restrict__ u,
              const u64t* __restrict__ v, float norm) {
  long i = (long)blockIdx.x * 256 + threadIdx.x;
  if (i >= 4L * 1025 * 1025) return;
  const int b = (int)(i / 1050625);
  const long r = i - (long)b * 1050625;
  const int n = (int)(r / 1025);
  const int m = (int)(r - (long)n * 1025);
  const float uu = __uint_as_float((unsigned)u[b * 1025 + n]);
  const float vv = __uint_as_float((unsigned)v[b * 1025 + m]);
  C[i] += uu + vv - norm;
}

// ---------------- host ----------------
extern "C" void kernel_launch(void* const* d_in, const int* in_sizes, int n_in,
                              void* d_out, int out_size, void* d_ws, size_t ws_size,
                              hipStream_t stream) {
  (void)in_sizes; (void)n_in; (void)out_size;
  const float* descs0 = (const float*)d_in[0];
  const float* descs1 = (const float*)d_in[1];
  const float* Wq = (const float*)d_in[2];
  const float* bq = (const float*)d_in[3];
  const float* Wk = (const float*)d_in[4];
  const float* bk = (const float*)d_in[5];
  const float* Wv = (const float*)d_in[6];
  const float* bvv = (const float*)d_in[7];
  const float* Wm = (const float*)d_in[8];
  const float* bm = (const float*)d_in[9];
  const float* W1 = (const float*)d_in[10];
  const float* b1 = (const float*)d_in[11];
  const float* W2 = (const float*)d_in[12];
  const float* b2 = (const float*)d_in[13];
  const float* Wf = (const float*)d_in[14];
  const float* bff = (const float*)d_in[15];
  const float* alpha = (const float*)d_in[16];

  char* ws = (char*)d_ws;
  size_t off = 0;
  auto alloc = [&](size_t bytes) -> void* {
    off = (off + 255) & ~(size_t)255;
    void* p = ws + off;
    off += bytes;
    return p;
  };

  // adaptive attention chunking: full scores buffer needs ~206 MB of ws
  const bool full = ws_size >= ((size_t)210 << 20);
  const int nch = full ? 1 : 4;
  const int chImgs = full ? 8 : 2;
  const size_t scrBytes = full ? ((size_t)chImgs * 8 * 1024 * 1024 * 2)  // 128 MB
                               : 50331648;                               // 48 MB

  bf16* wL = (bf16*)alloc(2621440L * 2);           // rotating per-layer weights (5 MB)
  float* bqkv = (float*)alloc(1536 * 4);
  bf16* WfB = (bf16*)alloc(512L * 512 * 2);
  float* Xf = (float*)alloc(8L * 1024 * 512 * 4);  // fp32 residual stream
  bf16* Yb = (bf16*)alloc(8L * 1024 * 1024 * 2);   // [img][n][1024]: 0:512 x, 512:1024 msg
  bf16* QKVb = (bf16*)alloc(8L * 1024 * 1536 * 2); // [token][1536] q|k|v
  bf16* vchan = (bf16*)alloc(8L * 1024 * 512 * 2); // [img][512ch][1024tok]
  bf16* Ob = (bf16*)alloc(8L * 1024 * 512 * 2);    // attn out [token][512]
  char* SCR = (char*)alloc(scrBytes);              // scores / T1+Zb / Ch+CTh+mproj
  float* stats = (float*)alloc(8L * 2048 * 4);
  u64t* u = (u64t*)alloc(4L * 1025 * 8);           // (tag<<32 | f32) pairs
  u64t* v = (u64t*)alloc(4L * 1025 * 8);

  bf16* wqkv = wL;                 // [1536][512]
  bf16* wm = wL + 786432;
  bf16* w1 = wL + 1048576;
  bf16* w2 = wL + 2097152;
  __half* scoresH = (__half*)SCR;  // chunk: chImgs*8*1024*1024 fp16
  bf16* probsB = (bf16*)SCR;
  float* T1 = (float*)SCR;                 // 32 MB
  bf16* Zb = (bf16*)(SCR + 33554432);      // 16 MB
  __half* Ch = (__half*)SCR;               // 8.4 MB fp16 couplings (post-layers)
  __half* CTh = (__half*)(SCR + 8405248);  // 8.4 MB fp16 transposed
  bf16* mproj = (bf16*)(SCR + 33554432);   // 8 MB (post-layers)
  float* coup = (float*)d_out;

  cvt_f2b<<<512, 256, 0, stream>>>(Wf, WfB, 512L * 512);
  init_x<<<4096, 256, 0, stream>>>(descs0, descs1, Xf, Yb);

  auto gemm = [&](int ntile, const bf16* A, const bf16* B, int M, int N, int K,
                  int lda, int ldb, long sAimg, long sAh, long sBimg, long sBh,
                  int Z, int ZH, int cross, float scale, const float* bias,
                  float* Cf, int ldcf, long sCfImg, long sCfH,
                  bf16* Cb, int ldcb, long sCbImg, long sCbH,
                  __half* Ch_, int ldch, long sChImg, long sChH,
                  const float* resid) {
    GemmP p;
    p.A = A; p.B = B; p.M = M; p.N = N; p.K = K; p.lda = lda; p.ldb = ldb;
    p.sAimg = sAimg; p.sAh = sAh; p.sBimg = sBimg; p.sBh = sBh;
    p.ZH = ZH; p.cross = cross; p.scale = scale; p.bias = bias;
    p.Cf = Cf; p.ldcf = ldcf; p.sCfImg = sCfImg; p.sCfH = sCfH;
    p.Cb = Cb; p.ldcb = ldcb; p.sCbImg = sCbImg; p.sCbH = sCbH;
    p.Ch = Ch_; p.ldch = ldch; p.sChImg = sChImg; p.sChH = sChH;
    p.resid = resid;
    dim3 g((unsigned)((N + ntile - 1) / ntile), (unsigned)((M + 127) / 128), (unsigned)Z);
    if (ntile == 128) gemm_bt<128><<<g, 256, 0, stream>>>(p);
    else gemm_bt<64><<<g, 256, 0, stream>>>(p);
  };

  for (int i = 0; i < 12; i++) {
    const int cross = i & 1;  // NAMES = self,cross,self,...
    cvt_layer<<<10247, 256, 0, stream>>>(Wq, Wk, Wv, Wm, W1, W2, bq, bk, bvv, i, wL, bqkv);

    // fused QKV: [8192,1536] = Yb[:, :512] x Wqkv^T
    gemm(128, Yb, wqkv, 8192, 1536, 512, 1024, 512, 0, 0, 0, 0, 1, 1, 0, 1.f, bqkv,
         nullptr, 0, 0, 0, QKVb, 1536, 0, 0, nullptr, 0, 0, 0, nullptr);
    // v channels -> channel-major
    transpose_2b<<<dim3(8, 16, 8), 256, 0, stream>>>((const unsigned short*)(QKVb + 1024),
                                                     1536, (unsigned short*)vchan);
    for (int c = 0; c < nch; c++) {
      const long tokOfs = (long)c * chImgs * 1024 * 1536;
      // scores[limg][h][n][m] = q.k^T / 8  (fp16)
      gemm(128, QKVb + tokOfs, QKVb + tokOfs + 512, 1024, 1024, 64, 1536, 1536,
           1572864, 64, 1572864, 64, chImgs * 8, 8, cross,
           0.125f, nullptr,
           nullptr, 0, 0, 0, nullptr, 0, 0, 0,
           scoresH, 1024, 8L * 1048576, 1048576, nullptr);
      softmax_rows<<<chImgs * 2048, 256, 0, stream>>>(scoresH);
      // O[limg][n][h*64+dh] = probs x V  (NTILE=64: no wasted MFMA on N=64)
      gemm(64, probsB, vchan + (long)c * chImgs * 524288, 1024, 64, 1024, 1024, 1024,
           8L * 1048576, 1048576, 524288, 65536, chImgs * 8, 8, cross,
           1.f, nullptr,
           nullptr, 0, 0, 0, Ob + (long)c * chImgs * 524288, 512, 524288, 64,
           nullptr, 0, 0, 0, nullptr);
    }
    // msg -> Yb[:, 512:1024]  (wm pre-permuted for head-merge order)
    gemm(128, Ob, wm, 8192, 512, 512, 512, 512, 0, 0, 0, 0, 1, 1, 0, 1.f, bm + i * 512,
         nullptr, 0, 0, 0, Yb + 512, 1024, 0, 0, nullptr, 0, 0, 0, nullptr);
    // T1 = W1 x [x; msg] + b1 (fp32)
    gemm(128, Yb, w1, 8192, 1024, 1024, 1024, 1024, 0, 0, 0, 0, 1, 1, 0, 1.f, b1 + i * 1024,
         T1, 1024, 0, 0, nullptr, 0, 0, 0, nullptr, 0, 0, 0, nullptr);
    hipMemsetAsync(stats, 0, 8L * 2048 * 4, stream);
    in_stats<<<dim3(4, 8, 8), 256, 0, stream>>>(T1, stats);
    in_apply<<<8192, 256, 0, stream>>>(T1, stats, Zb);
    // x += W2 z + b2 : fp32 residual into Xf, bf16 mirror into Yb[:, :512]
    gemm(128, Zb, w2, 8192, 512, 1024, 1024, 1024, 0, 0, 0, 0, 1, 1, 0, 1.f, b2 + i * 512,
         Xf, 512, 0, 0, Yb, 1024, 0, 0, nullptr, 0, 0, 0, Xf);
  }

  // final projection + score matrix into d_out
  gemm(128, Yb, WfB, 8192, 512, 512, 1024, 512, 0, 0, 0, 0, 1, 1, 0, 1.f, bff,
       nullptr, 0, 0, 0, mproj, 512, 0, 0, nullptr, 0, 0, 0, nullptr);
  gemm(128, mproj, mproj + 524288, 1024, 1024, 512, 512, 512,
       1048576, 0, 1048576, 0, 4, 1, 0,
       0.044194173824159216f, nullptr,
       coup, 1025, 1050625, 0, nullptr, 0, 0, 0, nullptr, 0, 0, 0, nullptr);
  fill_bins<<<17, 256, 0, stream>>>(coup, alpha);
  coup_to_fp16<<<dim3(33, 33, 4), 256, 0, stream>>>(coup, Ch, CTh);

  hipMemsetAsync(u, 0, 4L * 1025 * 8, stream);
  hipMemsetAsync(v, 0, 4L * 1025 * 8, stream);
  const float NORM = -logf(2048.f);
  const float LOGN = logf(1024.f);
  int iters = 100;
  void* args[] = {(void*)&Ch, (void*)&CTh, (void*)&u, (void*)&v,
                  (void*)&NORM, (void*)&LOGN, (void*)&iters};
  hipLaunchCooperativeKernel((void*)sinkhorn_pers, dim3(SK_BLOCKS), dim3(1024), args, 0, stream);
  ot_final<<<16417, 256, 0, stream>>>(coup, u, v, NORM);
}

// Round 4
// 3660.909 us; speedup vs baseline: 1.5694x; 1.2728x over previous
//
#include <hip/hip_runtime.h>
#include <hip/hip_bf16.h>
#include <hip/hip_fp16.h>
#include <cmath>

using bf16 = __hip_bfloat16;
typedef __attribute__((ext_vector_type(8))) short short8;
typedef __attribute__((ext_vector_type(4))) float floatx4;
typedef unsigned long long u64t;

__device__ __forceinline__ void lds_load16(void* lds, const void* g) {
  __builtin_amdgcn_global_load_lds(
      (const __attribute__((address_space(1))) void*)g,
      (__attribute__((address_space(3))) void*)lds, 16, 0, 0);
}

// ---------------- generic BT GEMM: C[M][N] = scale*(A[M][K] x B[N][K]^T) + bias ----------
struct GemmP {
  const bf16* A; const bf16* B;
  int M, N, K, lda, ldb;
  long sAimg, sAh, sBimg, sBh;
  int ZH, cross;
  float scale;
  const float* bias;
  float* Cf; int ldcf; long sCfImg, sCfH;
  bf16* Cb; int ldcb; long sCbImg, sCbH;
  __half* Ch; int ldch; long sChImg, sChH;
  const float* resid;  // fp32, same indexing as Cf
};

template <int NTILE>  // 128: 4 waves x (64x64); 64: 4 waves x (32x64)
__global__ __launch_bounds__(256, 2)
void gemm_bt(GemmP p) {
  __shared__ __align__(16) bf16 As[128 * 32];
  __shared__ __align__(16) bf16 Bs[NTILE * 32];
  constexpr int MI = (NTILE == 128) ? 4 : 2;
  const int z = blockIdx.z;
  const int imgA = z / p.ZH;
  const int h = z - imgA * p.ZH;
  const int imgB = imgA ^ p.cross;
  const bf16* Ab = p.A + (long)imgA * p.sAimg + (long)h * p.sAh;
  const bf16* Bb = p.B + (long)imgB * p.sBimg + (long)h * p.sBh;
  const int m0 = blockIdx.y * 128, n0 = blockIdx.x * NTILE;
  const int t = threadIdx.x, w = t >> 6, l = t & 63;
  const int lr = l >> 2, lk = (l & 3) * 8;   // staging: row-in-chunk, k-elem offset
  const int fr = l & 15, fk = (l >> 4) * 8;  // fragment: row-in-16tile, k offset

  const bf16* aG0 = Ab + (long)(m0 + w * 16 + lr) * p.lda + lk;
  const bf16* aG1 = aG0 + (long)64 * p.lda;
  const bf16* bG0 = Bb + (long)(n0 + w * 16 + lr) * p.ldb + lk;
  const bf16* bG1 = bG0 + (long)64 * p.ldb;
  bf16* aL0 = &As[w * 16 * 32];
  bf16* aL1 = &As[(w + 4) * 16 * 32];
  bf16* bL0 = &Bs[w * 16 * 32];
  bf16* bL1 = &Bs[(w + 4) * 16 * 32];
  const int wr = (NTILE == 128) ? (w >> 1) * 64 : w * 32;
  const int wc = (NTILE == 128) ? (w & 1) * 64 : 0;

  floatx4 zero4 = {0.f, 0.f, 0.f, 0.f};
  floatx4 acc[MI][4];
#pragma unroll
  for (int i = 0; i < MI; i++)
#pragma unroll
    for (int j = 0; j < 4; j++) acc[i][j] = zero4;

  for (int k0 = 0; k0 < p.K; k0 += 32) {
    lds_load16(aL0, aG0 + k0);
    lds_load16(aL1, aG1 + k0);
    lds_load16(bL0, bG0 + k0);
    if (NTILE == 128) lds_load16(bL1, bG1 + k0);
    __syncthreads();
    short8 af[MI], bfv[4];
#pragma unroll
    for (int i = 0; i < MI; i++)
      af[i] = *(const short8*)&As[(wr + i * 16 + fr) * 32 + fk];
#pragma unroll
    for (int j = 0; j < 4; j++)
      bfv[j] = *(const short8*)&Bs[(wc + j * 16 + fr) * 32 + fk];
#pragma unroll
    for (int i = 0; i < MI; i++)
#pragma unroll
      for (int j = 0; j < 4; j++)
        acc[i][j] = __builtin_amdgcn_mfma_f32_16x16x32_bf16(af[i], bfv[j], acc[i][j], 0, 0, 0);
    __syncthreads();
  }

  // epilogue: D[row][col], col = lane&15, row = (lane>>4)*4 + r  [m89-verified layout]
  const int cl = l & 15, rq = (l >> 4) * 4;
  const long cfBase = (long)imgA * p.sCfImg + (long)h * p.sCfH;
  const long cbBase = (long)imgA * p.sCbImg + (long)h * p.sCbH;
  const long chBase = (long)imgA * p.sChImg + (long)h * p.sChH;
#pragma unroll
  for (int j = 0; j < 4; j++) {
    const int col = n0 + wc + j * 16 + cl;
    if (col >= p.N) continue;
    const float bv = p.bias ? p.bias[col] : 0.f;
#pragma unroll
    for (int i = 0; i < MI; i++) {
#pragma unroll
      for (int r = 0; r < 4; r++) {
        const int row = m0 + wr + i * 16 + rq + r;
        float val = acc[i][j][r] * p.scale + bv;
        if (p.resid) val += p.resid[cfBase + (long)row * p.ldcf + col];
        if (p.Cf) p.Cf[cfBase + (long)row * p.ldcf + col] = val;
        if (p.Cb) p.Cb[cbBase + (long)row * p.ldcb + col] = __float2bfloat16(val);
        if (p.Ch) p.Ch[chBase + (long)row * p.ldch + col] = __float2half(val);
      }
    }
  }
}

// ---------------- fused flash attention ----------------
// grid: x = q-tile (8 tiles of 128 rows), z = img*8 + head. block = 256 (4 waves).
// Per block: Q[128][64] LDS-resident; loop 16 KV-tiles of 64 keys: S=QK^T (MFMA),
// online softmax in-register (16-lane shfl groups match C-layout col=lane&15),
// P routed via LDS (wave-local rows) to A-frags, O += P*V (MFMA).
// All LDS tiles use row-XOR swizzle byte^=((row&7)<<4): conflict-free ds_read_b128.
// Replaces: scores gemm (128 MB fp16 write), softmax_rows (256 MB), PV gemm read.
__global__ __launch_bounds__(256, 2)
void attn_fused(const bf16* __restrict__ QKV, const bf16* __restrict__ vchan,
                bf16* __restrict__ Ob, int cross) {
  __shared__ __align__(16) bf16 Qs[128 * 64];
  __shared__ __align__(16) bf16 Ks[64 * 64];
  __shared__ __align__(16) bf16 Vs[64 * 64];
  __shared__ __align__(16) bf16 Ps[128 * 64];
  const int z = blockIdx.z;
  const int img = z >> 3, h = z & 7;
  const int imgB = img ^ cross;
  const int q0 = blockIdx.x * 128;
  const int t = threadIdx.x, w = t >> 6, l = t & 63;
  const int g = l >> 4, fr = l & 15;
  const int wr = w * 32;

  // ---- stage Q tile [128 rows][64 d], swizzled ----
  {
    const bf16* src = QKV + ((long)(img * 1024 + q0)) * 1536 + h * 64;
#pragma unroll
    for (int k = 0; k < 4; k++) {
      const int chunk = t + k * 256;  // 0..1023 = 128 rows x 8 chunks
      const int row = chunk >> 3, c16 = chunk & 7;
      const short8 vd = *(const short8*)(src + (long)row * 1536 + c16 * 8);
      *(short8*)((char*)Qs + row * 128 + ((c16 * 16) ^ ((row & 7) << 4))) = vd;
    }
  }
  __syncthreads();

  // hoist Q A-frags (constant across KV loop): rows wr+i*16+fr, k-bytes ks*64+g*16
  short8 qf[2][2];
#pragma unroll
  for (int i = 0; i < 2; i++)
#pragma unroll
    for (int ks = 0; ks < 2; ks++) {
      const int row = wr + i * 16 + fr;
      qf[i][ks] = *(const short8*)((const char*)Qs + row * 128 +
                                   ((ks * 64 + g * 16) ^ ((row & 7) << 4)));
    }

  floatx4 zero4 = {0.f, 0.f, 0.f, 0.f};
  floatx4 Oa[2][4];
  float m_run[2][4], l_run[2][4];
#pragma unroll
  for (int i = 0; i < 2; i++)
#pragma unroll
    for (int r = 0; r < 4; r++) { m_run[i][r] = -3.0e38f; l_run[i][r] = 0.f; }
#pragma unroll
  for (int i = 0; i < 2; i++)
#pragma unroll
    for (int jd = 0; jd < 4; jd++) Oa[i][jd] = zero4;

  const bf16* ksrc0 = QKV + ((long)(imgB * 1024)) * 1536 + 512 + h * 64;
  const bf16* vsrc0 = vchan + (long)imgB * 524288 + (long)(h * 64) * 1024;

  for (int kv = 0; kv < 16; kv++) {
    const int kv0 = kv * 64;
    // ---- stage K [64 keys][64 d] and V^T [64 d][64 keys], swizzled ----
#pragma unroll
    for (int k = 0; k < 2; k++) {
      const int ch = t + k * 256;  // 0..511 = 64 rows x 8 chunks
      const int row = ch >> 3, c16 = ch & 7;
      const short8 vd = *(const short8*)(ksrc0 + (long)(kv0 + row) * 1536 + c16 * 8);
      *(short8*)((char*)Ks + row * 128 + ((c16 * 16) ^ ((row & 7) << 4))) = vd;
    }
#pragma unroll
    for (int k = 0; k < 2; k++) {
      const int ch = t + k * 256;
      const int row = ch >> 3, c16 = ch & 7;  // row = d channel
      const short8 vd = *(const short8*)(vsrc0 + (long)row * 1024 + kv0 + c16 * 8);
      *(short8*)((char*)Vs + row * 128 + ((c16 * 16) ^ ((row & 7) << 4))) = vd;
    }
    __syncthreads();

    // ---- S = Q K^T ----
    floatx4 sa[2][4];
#pragma unroll
    for (int i = 0; i < 2; i++)
#pragma unroll
      for (int j = 0; j < 4; j++) sa[i][j] = zero4;
    short8 bk[4][2];
#pragma unroll
    for (int j = 0; j < 4; j++)
#pragma unroll
      for (int ks = 0; ks < 2; ks++) {
        const int row = j * 16 + fr;  // key within tile
        bk[j][ks] = *(const short8*)((const char*)Ks + row * 128 +
                                     ((ks * 64 + g * 16) ^ ((row & 7) << 4)));
      }
#pragma unroll
    for (int i = 0; i < 2; i++)
#pragma unroll
      for (int j = 0; j < 4; j++)
#pragma unroll
        for (int ks = 0; ks < 2; ks++)
          sa[i][j] = __builtin_amdgcn_mfma_f32_16x16x32_bf16(qf[i][ks], bk[j][ks], sa[i][j], 0, 0, 0);

    // ---- online softmax: rows owned per (i,r) across 16-lane col groups ----
#pragma unroll
    for (int i = 0; i < 2; i++) {
#pragma unroll
      for (int r = 0; r < 4; r++) {
        float mx = -3.0e38f;
#pragma unroll
        for (int j = 0; j < 4; j++) {
          sa[i][j][r] *= 0.125f;
          mx = fmaxf(mx, sa[i][j][r]);
        }
#pragma unroll
        for (int o = 1; o < 16; o <<= 1) mx = fmaxf(mx, __shfl_xor(mx, o));
        const float mnew = fmaxf(m_run[i][r], mx);
        const float corr = __expf(m_run[i][r] - mnew);
        m_run[i][r] = mnew;
        float ps = 0.f;
#pragma unroll
        for (int j = 0; j < 4; j++) {
          const float pv = __expf(sa[i][j][r] - mnew);
          sa[i][j][r] = pv;
          ps += pv;
        }
#pragma unroll
        for (int o = 1; o < 16; o <<= 1) ps += __shfl_xor(ps, o);
        l_run[i][r] = l_run[i][r] * corr + ps;
#pragma unroll
        for (int jd = 0; jd < 4; jd++) Oa[i][jd][r] *= corr;
      }
    }

    // ---- P -> LDS (wave-local rows; swizzled scatter) ----
#pragma unroll
    for (int i = 0; i < 2; i++)
#pragma unroll
      for (int j = 0; j < 4; j++)
#pragma unroll
        for (int r = 0; r < 4; r++) {
          const int row = wr + i * 16 + g * 4 + r;
          const int colB = j * 32 + fr * 2;
          *(bf16*)((char*)Ps + row * 128 + (colB ^ ((row & 7) << 4))) =
              __float2bfloat16(sa[i][j][r]);
        }

    // ---- O += P V (P rows wave-local; compiler inserts lgkmcnt for LDS dep) ----
    short8 pf[2][2], vf[4][2];
#pragma unroll
    for (int i = 0; i < 2; i++)
#pragma unroll
      for (int ks = 0; ks < 2; ks++) {
        const int row = wr + i * 16 + fr;
        pf[i][ks] = *(const short8*)((const char*)Ps + row * 128 +
                                     ((ks * 64 + g * 16) ^ ((row & 7) << 4)));
      }
#pragma unroll
    for (int jd = 0; jd < 4; jd++)
#pragma unroll
      for (int ks = 0; ks < 2; ks++) {
        const int row = jd * 16 + fr;  // d channel
        vf[jd][ks] = *(const short8*)((const char*)Vs + row * 128 +
                                      ((ks * 64 + g * 16) ^ ((row & 7) << 4)));
      }
#pragma unroll
    for (int i = 0; i < 2; i++)
#pragma unroll
      for (int jd = 0; jd < 4; jd++)
#pragma unroll
        for (int ks = 0; ks < 2; ks++)
          Oa[i][jd] = __builtin_amdgcn_mfma_f32_16x16x32_bf16(pf[i][ks], vf[jd][ks], Oa[i][jd], 0, 0, 0);
    __syncthreads();  // protect Ks/Vs before next-iter staging
  }

  // ---- epilogue: O /= l, write Ob[img][token][h*64+d] ----
#pragma unroll
  for (int i = 0; i < 2; i++) {
#pragma unroll
    for (int r = 0; r < 4; r++) {
      const float inv = 1.f / l_run[i][r];
      const int qrow = q0 + wr + i * 16 + g * 4 + r;
      bf16* dst = Ob + ((long)img * 1024 + qrow) * 512 + h * 64;
#pragma unroll
      for (int jd = 0; jd < 4; jd++)
        dst[jd * 16 + fr] = __float2bfloat16(Oa[i][jd][r] * inv);
    }
  }
}

// ---------------- elementwise / helper kernels ----------------
__global__ __launch_bounds__(256)
void cvt_f2b(const float* __restrict__ in, bf16* __restrict__ out, long n) {
  long i = (long)blockIdx.x * 256 + threadIdx.x;
  const long stride = (long)gridDim.x * 256;
  for (; i < n; i += stride) out[i] = __float2bfloat16(in[i]);
}

// fused per-layer weight conversion into rotating buffer (5 MB)
__global__ __launch_bounds__(256)
void cvt_layer(const float* __restrict__ Wq, const float* __restrict__ Wk,
               const float* __restrict__ Wv, const float* __restrict__ Wm,
               const float* __restrict__ W1, const float* __restrict__ W2,
               const float* __restrict__ bq, const float* __restrict__ bk,
               const float* __restrict__ bv,
               int layer, bf16* __restrict__ out, float* __restrict__ bqkv) {
  const long i = (long)blockIdx.x * 256 + threadIdx.x;
  if (i >= 2621440L + 1536) return;
  if (i >= 2621440L) {
    const int j = (int)(i - 2621440L);
    float b;
    if (j < 512) b = bq[layer * 512 + j];
    else if (j < 1024) b = bk[layer * 512 + j - 512];
    else b = bv[layer * 512 + j - 1024];
    bqkv[j] = b;
    return;
  }
  float v;
  if (i < 262144) {
    v = Wq[(long)layer * 262144 + i];
  } else if (i < 524288) {
    v = Wk[(long)layer * 262144 + i - 262144];
  } else if (i < 786432) {
    v = Wv[(long)layer * 262144 + i - 524288];
  } else if (i < 1048576) {
    const long j = i - 786432;
    const int o = (int)(j >> 9), cp = (int)(j & 511);
    v = Wm[(long)layer * 262144 + o * 512 + (cp & 63) * 8 + (cp >> 6)];
  } else if (i < 2097152) {
    v = W1[(long)layer * 1048576 + i - 1048576];
  } else {
    v = W2[(long)layer * 524288 + i - 2097152];
  }
  out[i] = __float2bfloat16(v);
}

__global__ __launch_bounds__(256)
void init_x(const float* __restrict__ d0, const float* __restrict__ d1,
            float* __restrict__ Xf, bf16* __restrict__ Yb) {
  long i = (long)blockIdx.x * 256 + threadIdx.x;
  const long stride = (long)gridDim.x * 256;
  const long n = 8L * 1024 * 512;
  for (; i < n; i += stride) {
    const int d = (int)(i & 511);
    const long nn = i >> 9;  // img*1024 + row
    const int img = (int)(nn >> 10);
    const int row = (int)(nn & 1023);
    const int b = img >> 1, s = img & 1;
    const float v = (s ? d1 : d0)[((long)b * 1024 + row) * 512 + d];
    Xf[i] = v;
    Yb[(nn << 10) + d] = __float2bfloat16(v);
  }
}

// transpose [8][1024][512-cols-of-ldi] (2-byte elems) -> [8][512][1024]
__global__ __launch_bounds__(256)
void transpose_2b(const unsigned short* __restrict__ in, int ldi,
                  unsigned short* __restrict__ out) {
  __shared__ unsigned short tile[64][65];
  const int img = blockIdx.z;
  const int m0 = blockIdx.y * 64, c0 = blockIdx.x * 64;
  const int col = threadIdx.x & 63, r0 = threadIdx.x >> 6;
  const unsigned short* ip = in + ((long)img * 1024 + m0) * ldi + c0;
#pragma unroll
  for (int i = 0; i < 16; i++) { int r = r0 + i * 4; tile[r][col] = ip[(long)r * ldi + col]; }
  __syncthreads();
  unsigned short* op = out + ((long)img * 512 + c0) * 1024 + m0;
#pragma unroll
  for (int i = 0; i < 16; i++) { int r = r0 + i * 4; op[(long)r * 1024 + col] = tile[col][r]; }
}

// instance-norm stats: column sums over n per (img, channel); stats pre-zeroed
__global__ __launch_bounds__(256)
void in_stats(const float* __restrict__ T1, float* __restrict__ stats) {
  const int img = blockIdx.z;
  const int c = blockIdx.x * 256 + threadIdx.x;
  const int nb = blockIdx.y;
  const float* p = T1 + ((long)img * 1024 + nb * 128) * 1024 + c;
  float s = 0.f, s2 = 0.f;
#pragma unroll 4
  for (int i = 0; i < 128; i++) { const float x = p[(long)i * 1024]; s += x; s2 += x * x; }
  atomicAdd(&stats[img * 2048 + c], s);
  atomicAdd(&stats[img * 2048 + 1024 + c], s2);
}

__global__ __launch_bounds__(256)
void in_apply(const float* __restrict__ T1, const float* __restrict__ stats,
              bf16* __restrict__ Z) {
  long i = (long)blockIdx.x * 256 + threadIdx.x;
  const long stride = (long)gridDim.x * 256;
  for (; i < 8L * 1024 * 1024; i += stride) {
    const int c = (int)(i & 1023);
    const int img = (int)(i >> 20);
    const float mean = stats[img * 2048 + c] * (1.f / 1024.f);
    const float var = fmaxf(stats[img * 2048 + 1024 + c] * (1.f / 1024.f) - mean * mean, 0.f);
    const float zz = (T1[i] - mean) * rsqrtf(var + 1e-5f);
    Z[i] = __float2bfloat16(fmaxf(zz, 0.f));
  }
}

__global__ __launch_bounds__(256)
void fill_bins(float* C, const float* alpha) {
  const int i = blockIdx.x * 256 + threadIdx.x;
  if (i >= 4 * 1025) return;
  const float a = *alpha;
  const int b = i / 1025, n = i - b * 1025;
  C[((long)b * 1025 + n) * 1025 + 1024] = a;
  C[((long)b * 1025 + 1024) * 1025 + n] = a;
}

// fp32 coupling -> fp16 straight copy + fp16 transpose (for L2-resident sinkhorn)
__global__ __launch_bounds__(256)
void coup_to_fp16(const float* __restrict__ in, __half* __restrict__ outN,
                  __half* __restrict__ outT) {
  __shared__ float tile[32][33];
  const int b = blockIdx.z;
  const int x0 = blockIdx.x * 32, y0 = blockIdx.y * 32;
  const int lx = threadIdx.x & 31, ly = threadIdx.x >> 5;  // ly 0..7
#pragma unroll
  for (int i = 0; i < 4; i++) {
    const int y = ly + i * 8;
    if (y0 + y < 1025 && x0 + lx < 1025) {
      const float vv = in[((long)b * 1025 + y0 + y) * 1025 + x0 + lx];
      tile[y][lx] = vv;
      outN[((long)b * 1025 + y0 + y) * 1025 + x0 + lx] = __float2half(vv);
    }
  }
  __syncthreads();
#pragma unroll
  for (int i = 0; i < 4; i++) {
    const int y = ly + i * 8;
    if (x0 + y < 1025 && y0 + lx < 1025)
      outT[((long)b * 1025 + x0 + y) * 1025 + y0 + lx] = __float2half(tile[lx][y]);
  }
}

// -------- persistent Sinkhorn (r9 structure: per-lane spin on tagged u64 entries) ----
#define SK_BLOCKS 256

#define SK_ROUND(CREG, CLAST, XREG, XLAST, SRC, DST)                            \
  {                                                                             \
    u64t pr;                                                                    \
    while ((unsigned)((pr = __hip_atomic_load(&(SRC)[t], __ATOMIC_RELAXED,      \
                                              __HIP_MEMORY_SCOPE_AGENT)) >>    \
                      32) != tag)                                               \
      __builtin_amdgcn_s_sleep(1);                                              \
    sv[t] = __uint_as_float((unsigned)pr);                                      \
    if (t == 0) {                                                               \
      u64t qr;                                                                  \
      while ((unsigned)((qr = __hip_atomic_load(&(SRC)[1024], __ATOMIC_RELAXED, \
                                                __HIP_MEMORY_SCOPE_AGENT)) >>  \
                        32) != tag)                                             \
        __builtin_amdgcn_s_sleep(1);                                            \
      sv[1024] = __uint_as_float((unsigned)qr);                                 \
    }                                                                           \
    __syncthreads();                                                            \
    float M = (l == 0) ? ((CLAST) + sv[1024]) : -3.0e38f;                       \
    const float extra = M;                                                      \
    float x[16];                                                                \
    _Pragma("unroll") for (int i = 0; i < 16; i++) {                            \
      x[i] = (CREG)[i] + sv[l + 64 * i];                                        \
      M = fmaxf(M, x[i]);                                                       \
    }                                                                           \
    _Pragma("unroll") for (int o = 32; o >= 1; o >>= 1)                         \
        M = fmaxf(M, __shfl_xor(M, o));                                         \
    float S = (l == 0) ? __expf(extra - M) : 0.f;                               \
    _Pragma("unroll") for (int i = 0; i < 16; i++) S += __expf(x[i] - M);       \
    _Pragma("unroll") for (int o = 32; o >= 1; o >>= 1) S += __shfl_xor(S, o);  \
    if (l == 0) {                                                               \
      const float val = norm - (M + __logf(S));                                 \
      const u64t pk = ((u64t)(tag + 1) << 32) | (u64t)__float_as_uint(val);     \
      __hip_atomic_store(&(DST)[lw], pk, __ATOMIC_RELAXED,                      \
                         __HIP_MEMORY_SCOPE_AGENT);                             \
    }                                                                           \
    if (xtra) {                                                                 \
      float M2 = (l == 0) ? ((XLAST) + sv[1024]) : -3.0e38f;                    \
      const float e2 = M2;                                                      \
      float y[16];                                                              \
      _Pragma("unroll") for (int i = 0; i < 16; i++) {                          \
        y[i] = (XREG)[i] + sv[l + 64 * i];                                      \
        M2 = fmaxf(M2, y[i]);                                                   \
      }                                                                         \
      _Pragma("unroll") for (int o = 32; o >= 1; o >>= 1)                       \
          M2 = fmaxf(M2, __shfl_xor(M2, o));                                    \
      float S2 = (l == 0) ? __expf(e2 - M2) : 0.f;                              \
      _Pragma("unroll") for (int i = 0; i < 16; i++) S2 += __expf(y[i] - M2);   \
      _Pragma("unroll") for (int o = 32; o >= 1; o >>= 1)                       \
          S2 += __shfl_xor(S2, o);                                              \
      if (l == 0) {                                                             \
        const float v2 = (logN + norm) - (M2 + __logf(S2));                     \
        const u64t pk2 = ((u64t)(tag + 1) << 32) | (u64t)__float_as_uint(v2);   \
        __hip_atomic_store(&(DST)[1024], pk2, __ATOMIC_RELAXED,                 \
                           __HIP_MEMORY_SCOPE_AGENT);                           \
      }                                                                         \
    }                                                                           \
    tag++;                                                                      \
    __syncthreads();                                                            \
  }

__global__ __launch_bounds__(1024)
void sinkhorn_pers(const __half* __restrict__ C, const __half* __restrict__ CT,
                   u64t* __restrict__ u, u64t* __restrict__ v,
                   float norm, float logN, int iters) {
  __shared__ float sv[1025];
  const int t = threadIdx.x;
  const int w = t >> 6, l = t & 63;
  const int b = blockIdx.x >> 6;   // batch 0..3
  const int kb = blockIdx.x & 63;  // block within batch
  const int lw = kb * 16 + w;      // wave's row within batch: 0..1023
  const __half* Cb = C + (long)b * 1050625;
  const __half* CTb = CT + (long)b * 1050625;
  u64t* ub = u + b * 1025;
  u64t* vb = v + b * 1025;

  float cr[16], cc[16];
  float clC, clT;
  {
    const __half* rc = Cb + (long)lw * 1025;
    const __half* rt = CTb + (long)lw * 1025;
#pragma unroll
    for (int i = 0; i < 16; i++) {
      cr[i] = __half2float(rc[l + 64 * i]);
      cc[i] = __half2float(rt[l + 64 * i]);
    }
    clC = (l == 0) ? __half2float(rc[1024]) : 0.f;
    clT = (l == 0) ? __half2float(rt[1024]) : 0.f;
  }
  const bool xtra = (lw == 0);
  float xrC[16], xrT[16], xlC = 0.f, xlT = 0.f;
  if (xtra) {
    const __half* rc = Cb + (long)1024 * 1025;
    const __half* rt = CTb + (long)1024 * 1025;
#pragma unroll
    for (int i = 0; i < 16; i++) {
      xrC[i] = __half2float(rc[l + 64 * i]);
      xrT[i] = __half2float(rt[l + 64 * i]);
    }
    if (l == 0) {
      xlC = __half2float(rc[1024]);
      xlT = __half2float(rt[1024]);
    }
  }

  unsigned tag = 0;
  for (int it = 0; it < iters; it++) {
    SK_ROUND(cr, clC, xrC, xlC, vb, ub);
    SK_ROUND(cc, clT, xrT, xlT, ub, vb);
  }
}

__global__ __launch_bounds__(256)
void ot_final(float* __restrict__ C, const u64t* __restrict__ u,
              const u64t* __restrict__ v, float norm) {
  long i = (long)blockIdx.x * 256 + threadIdx.x;
  if (i >= 4L * 1025 * 1025) return;
  const int b = (int)(i / 1050625);
  const long r = i - (long)b * 1050625;
  const int n = (int)(r / 1025);
  const int m = (int)(r - (long)n * 1025);
  const float uu = __uint_as_float((unsigned)u[b * 1025 + n]);
  const float vv = __uint_as_float((unsigned)v[b * 1025 + m]);
  C[i] += uu + vv - norm;
}

// ---------------- host ----------------
extern "C" void kernel_launch(void* const* d_in, const int* in_sizes, int n_in,
                              void* d_out, int out_size, void* d_ws, size_t ws_size,
                              hipStream_t stream) {
  (void)in_sizes; (void)n_in; (void)out_size; (void)ws_size;
  const float* descs0 = (const float*)d_in[0];
  const float* descs1 = (const float*)d_in[1];
  const float* Wq = (const float*)d_in[2];
  const float* bq = (const float*)d_in[3];
  const float* Wk = (const float*)d_in[4];
  const float* bk = (const float*)d_in[5];
  const float* Wv = (const float*)d_in[6];
  const float* bvv = (const float*)d_in[7];
  const float* Wm = (const float*)d_in[8];
  const float* bm = (const float*)d_in[9];
  const float* W1 = (const float*)d_in[10];
  const float* b1 = (const float*)d_in[11];
  const float* W2 = (const float*)d_in[12];
  const float* b2 = (const float*)d_in[13];
  const float* Wf = (const float*)d_in[14];
  const float* bff = (const float*)d_in[15];
  const float* alpha = (const float*)d_in[16];

  char* ws = (char*)d_ws;
  size_t off = 0;
  auto alloc = [&](size_t bytes) -> void* {
    off = (off + 255) & ~(size_t)255;
    void* p = ws + off;
    off += bytes;
    return p;
  };

  bf16* wL = (bf16*)alloc(2621440L * 2);           // rotating per-layer weights (5 MB)
  float* bqkv = (float*)alloc(1536 * 4);
  bf16* WfB = (bf16*)alloc(512L * 512 * 2);
  float* Xf = (float*)alloc(8L * 1024 * 512 * 4);  // fp32 residual stream
  bf16* Yb = (bf16*)alloc(8L * 1024 * 1024 * 2);   // [img][n][1024]: 0:512 x, 512:1024 msg
  bf16* QKVb = (bf16*)alloc(8L * 1024 * 1536 * 2); // [token][1536] q|k|v
  bf16* vchan = (bf16*)alloc(8L * 1024 * 512 * 2); // [img][512ch][1024tok]
  bf16* Ob = (bf16*)alloc(8L * 1024 * 512 * 2);    // attn out [token][512]
  char* SCR = (char*)alloc(50331648);              // 48 MB: T1+Zb / Ch+CTh+mproj
  float* stats = (float*)alloc(8L * 2048 * 4);
  u64t* u = (u64t*)alloc(4L * 1025 * 8);           // (tag<<32 | f32) pairs
  u64t* v = (u64t*)alloc(4L * 1025 * 8);

  bf16* wqkv = wL;                 // [1536][512]
  bf16* wm = wL + 786432;
  bf16* w1 = wL + 1048576;
  bf16* w2 = wL + 2097152;
  float* T1 = (float*)SCR;                 // 32 MB
  bf16* Zb = (bf16*)(SCR + 33554432);      // 16 MB
  __half* Ch = (__half*)SCR;               // 8.4 MB fp16 couplings (post-layers)
  __half* CTh = (__half*)(SCR + 8405248);  // 8.4 MB fp16 transposed
  bf16* mproj = (bf16*)(SCR + 33554432);   // 8 MB (post-layers)
  float* coup = (float*)d_out;

  cvt_f2b<<<512, 256, 0, stream>>>(Wf, WfB, 512L * 512);
  init_x<<<4096, 256, 0, stream>>>(descs0, descs1, Xf, Yb);

  auto gemm = [&](int ntile, const bf16* A, const bf16* B, int M, int N, int K,
                  int lda, int ldb, long sAimg, long sAh, long sBimg, long sBh,
                  int Z, int ZH, int cross, float scale, const float* bias,
                  float* Cf, int ldcf, long sCfImg, long sCfH,
                  bf16* Cb, int ldcb, long sCbImg, long sCbH,
                  __half* Ch_, int ldch, long sChImg, long sChH,
                  const float* resid) {
    GemmP p;
    p.A = A; p.B = B; p.M = M; p.N = N; p.K = K; p.lda = lda; p.ldb = ldb;
    p.sAimg = sAimg; p.sAh = sAh; p.sBimg = sBimg; p.sBh = sBh;
    p.ZH = ZH; p.cross = cross; p.scale = scale; p.bias = bias;
    p.Cf = Cf; p.ldcf = ldcf; p.sCfImg = sCfImg; p.sCfH = sCfH;
    p.Cb = Cb; p.ldcb = ldcb; p.sCbImg = sCbImg; p.sCbH = sCbH;
    p.Ch = Ch_; p.ldch = ldch; p.sChImg = sChImg; p.sChH = sChH;
    p.resid = resid;
    dim3 g((unsigned)((N + ntile - 1) / ntile), (unsigned)((M + 127) / 128), (unsigned)Z);
    if (ntile == 128) gemm_bt<128><<<g, 256, 0, stream>>>(p);
    else gemm_bt<64><<<g, 256, 0, stream>>>(p);
  };

  for (int i = 0; i < 12; i++) {
    const int cross = i & 1;  // NAMES = self,cross,self,...
    cvt_layer<<<10247, 256, 0, stream>>>(Wq, Wk, Wv, Wm, W1, W2, bq, bk, bvv, i, wL, bqkv);

    // fused QKV: [8192,1536] = Yb[:, :512] x Wqkv^T
    gemm(128, Yb, wqkv, 8192, 1536, 512, 1024, 512, 0, 0, 0, 0, 1, 1, 0, 1.f, bqkv,
         nullptr, 0, 0, 0, QKVb, 1536, 0, 0, nullptr, 0, 0, 0, nullptr);
    // v channels -> channel-major
    transpose_2b<<<dim3(8, 16, 8), 256, 0, stream>>>((const unsigned short*)(QKVb + 1024),
                                                     1536, (unsigned short*)vchan);
    // fused flash attention: QK^T -> online softmax -> PV, no materialized scores
    attn_fused<<<dim3(8, 1, 64), 256, 0, stream>>>(QKVb, vchan, Ob, cross);

    // msg -> Yb[:, 512:1024]  (wm pre-permuted for head-merge order)
    gemm(128, Ob, wm, 8192, 512, 512, 512, 512, 0, 0, 0, 0, 1, 1, 0, 1.f, bm + i * 512,
         nullptr, 0, 0, 0, Yb + 512, 1024, 0, 0, nullptr, 0, 0, 0, nullptr);
    // T1 = W1 x [x; msg] + b1 (fp32)
    gemm(128, Yb, w1, 8192, 1024, 1024, 1024, 1024, 0, 0, 0, 0, 1, 1, 0, 1.f, b1 + i * 1024,
         T1, 1024, 0, 0, nullptr, 0, 0, 0, nullptr, 0, 0, 0, nullptr);
    hipMemsetAsync(stats, 0, 8L * 2048 * 4, stream);
    in_stats<<<dim3(4, 8, 8), 256, 0, stream>>>(T1, stats);
    in_apply<<<8192, 256, 0, stream>>>(T1, stats, Zb);
    // x += W2 z + b2 : fp32 residual into Xf, bf16 mirror into Yb[:, :512]
    gemm(128, Zb, w2, 8192, 512, 1024, 1024, 1024, 0, 0, 0, 0, 1, 1, 0, 1.f, b2 + i * 512,
         Xf, 512, 0, 0, Yb, 1024, 0, 0, nullptr, 0, 0, 0, Xf);
  }

  // final projection + score matrix into d_out
  gemm(128, Yb, WfB, 8192, 512, 512, 1024, 512, 0, 0, 0, 0, 1, 1, 0, 1.f, bff,
       nullptr, 0, 0, 0, mproj, 512, 0, 0, nullptr, 0, 0, 0, nullptr);
  gemm(128, mproj, mproj + 524288, 1024, 1024, 512, 512, 512,
       1048576, 0, 1048576, 0, 4, 1, 0,
       0.044194173824159216f, nullptr,
       coup, 1025, 1050625, 0, nullptr, 0, 0, 0, nullptr, 0, 0, 0, nullptr);
  fill_bins<<<17, 256, 0, stream>>>(coup, alpha);
  coup_to_fp16<<<dim3(33, 33, 4), 256, 0, stream>>>(coup, Ch, CTh);

  hipMemsetAsync(u, 0, 4L * 1025 * 8, stream);
  hipMemsetAsync(v, 0, 4L * 1025 * 8, stream);
  const float NORM = -logf(2048.f);
  const float LOGN = logf(1024.f);
  int iters = 100;
  void* args[] = {(void*)&Ch, (void*)&CTh, (void*)&u, (void*)&v,
                  (void*)&NORM, (void*)&LOGN, (void*)&iters};
  hipLaunchCooperativeKernel((void*)sinkhorn_pers, dim3(SK_BLOCKS), dim3(1024), args, 0, stream);
  ot_final<<<16417, 256, 0, stream>>>(coup, u, v, NORM);
}